// Round 2
// baseline (5939.320 us; speedup 1.0000x reference)
//
#include <hip/hip_runtime.h>
#include <math.h>

namespace {

constexpr int kB = 512, kS = 200, kD = 256, kH = 4, kDH = 64;
constexpr int kM = kB * kS;           // 102400 rows
constexpr float kEps = 1e-8f;

__device__ __forceinline__ float bf2f(unsigned short s) {
  return __uint_as_float(((unsigned)s) << 16);
}
__device__ __forceinline__ unsigned short f2bf(float f) {
  unsigned u = __float_as_uint(f);
  unsigned r = (u + 0x7fffu + ((u >> 16) & 1u)) >> 16;
  return (unsigned short)r;
}

// seqs[b,s,:] = bf16((item_emb[idx]*16 + pos_emb[s]) * (idx != 0))
__global__ __launch_bounds__(64) void embed_kernel(
    const float* __restrict__ item_emb, const float* __restrict__ pos_emb,
    const int* __restrict__ log_seqs, unsigned short* __restrict__ seqs) {
  int bs = blockIdx.x;
  int s = bs % kS;
  int idx = log_seqs[bs];
  float msk = (idx != 0) ? 1.f : 0.f;
  int t = threadIdx.x;
  float4 a = reinterpret_cast<const float4*>(item_emb + (size_t)idx * kD)[t];
  float4 p = reinterpret_cast<const float4*>(pos_emb + (size_t)s * kD)[t];
  ushort4 r;
  r.x = f2bf((a.x * 16.f + p.x) * msk);
  r.y = f2bf((a.y * 16.f + p.y) * msk);
  r.z = f2bf((a.z * 16.f + p.z) * msk);
  r.w = f2bf((a.w * 16.f + p.w) * msk);
  reinterpret_cast<ushort4*>(seqs + (size_t)bs * kD)[t] = r;
}

// one wave per row; 4 elems per lane; bf16 in/out, f32 math
__global__ __launch_bounds__(64) void ln_kernel(
    const unsigned short* __restrict__ x, const float* __restrict__ g,
    const float* __restrict__ b, unsigned short* __restrict__ y) {
  int row = blockIdx.x;
  int t = threadIdx.x;
  ushort4 v4 = reinterpret_cast<const ushort4*>(x + (size_t)row * kD)[t];
  float vx = bf2f(v4.x), vy = bf2f(v4.y), vz = bf2f(v4.z), vw = bf2f(v4.w);
  float sm = vx + vy + vz + vw;
#pragma unroll
  for (int o = 32; o >= 1; o >>= 1) sm += __shfl_xor(sm, o);
  float mean = sm * (1.f / kD);
  float dx = vx - mean, dy = vy - mean, dz = vz - mean, dw = vw - mean;
  float vs = dx * dx + dy * dy + dz * dz + dw * dw;
#pragma unroll
  for (int o = 32; o >= 1; o >>= 1) vs += __shfl_xor(vs, o);
  float inv = rsqrtf(vs * (1.f / kD) + kEps);
  float4 gg = reinterpret_cast<const float4*>(g)[t];
  float4 bb = reinterpret_cast<const float4*>(b)[t];
  ushort4 r;
  r.x = f2bf(dx * inv * gg.x + bb.x);
  r.y = f2bf(dy * inv * gg.y + bb.y);
  r.z = f2bf(dz * inv * gg.z + bb.z);
  r.w = f2bf(dw * inv * gg.w + bb.w);
  reinterpret_cast<ushort4*>(y + (size_t)row * kD)[t] = r;
}

// C[M,N] = A[M,256] @ W[N,256]^T + bias. A,C,R bf16; W,bias f32; acc f32.
// MODE 0: +bias; 1: relu(+bias); 2: +bias+R; 3: (+bias+R)*mask(logseq!=0)
template <int MODE>
__global__ __launch_bounds__(256) void gemm_kernel(
    const unsigned short* __restrict__ A, const float* __restrict__ W,
    const float* __restrict__ bias, const unsigned short* __restrict__ R,
    const int* __restrict__ logseq, unsigned short* __restrict__ C, int N) {
  __shared__ float As[64][17];
  __shared__ float Ws[64][17];
  int m0 = blockIdx.x * 64;
  int n0 = blockIdx.y * 64;
  int tid = threadIdx.x;
  int lr = tid >> 2;          // 0..63: tile row being loaded
  int lc = (tid & 3) << 2;    // k-quad within 16
  int tm = tid >> 4, tn = tid & 15;
  float acc[4][4] = {};
  const unsigned short* Aptr = A + (size_t)(m0 + lr) * kD + lc;
  const float* Wptr = W + (size_t)(n0 + lr) * kD + lc;
  for (int k0 = 0; k0 < kD; k0 += 16) {
    ushort4 av = *reinterpret_cast<const ushort4*>(Aptr + k0);
    float4 wv = *reinterpret_cast<const float4*>(Wptr + k0);
    __syncthreads();
    As[lr][lc + 0] = bf2f(av.x); As[lr][lc + 1] = bf2f(av.y);
    As[lr][lc + 2] = bf2f(av.z); As[lr][lc + 3] = bf2f(av.w);
    Ws[lr][lc + 0] = wv.x; Ws[lr][lc + 1] = wv.y;
    Ws[lr][lc + 2] = wv.z; Ws[lr][lc + 3] = wv.w;
    __syncthreads();
#pragma unroll
    for (int k = 0; k < 16; ++k) {
      float a_[4], w_[4];
#pragma unroll
      for (int i = 0; i < 4; ++i) a_[i] = As[tm * 4 + i][k];
#pragma unroll
      for (int j = 0; j < 4; ++j) w_[j] = Ws[tn * 4 + j][k];
#pragma unroll
      for (int i = 0; i < 4; ++i)
#pragma unroll
        for (int j = 0; j < 4; ++j)
          acc[i][j] = fmaf(a_[i], w_[j], acc[i][j]);
    }
  }
#pragma unroll
  for (int i = 0; i < 4; ++i) {
    int m = m0 + tm * 4 + i;
    float msk = 1.f;
    if (MODE == 3) msk = (logseq[m] != 0) ? 1.f : 0.f;
#pragma unroll
    for (int j = 0; j < 4; ++j) {
      int n = n0 + tn * 4 + j;
      float v = acc[i][j] + bias[n];
      if (MODE == 1) v = fmaxf(v, 0.f);
      if (MODE >= 2) v += bf2f(R[(size_t)m * N + n]);
      if (MODE == 3) v *= msk;
      C[(size_t)m * N + n] = f2bf(v);
    }
  }
}

// one wave per (b, h, q-row). q/o in qo[M,256] (in-place: block touches only
// its own 64-elem slice). kv[M,512]: k cols 0..255, v cols 256..511. bf16.
__global__ __launch_bounds__(64) void attn_kernel(
    const unsigned short* __restrict__ qo_in,
    const unsigned short* __restrict__ kv,
    unsigned short* __restrict__ qo_out) {
  int blk = blockIdx.x;
  int b = blk / (kH * kS);
  int rem = blk % (kH * kS);
  int h = rem / kS;
  int qi = rem % kS;
  int t = threadIdx.x;
  __shared__ float qsh[kDH];
  __shared__ float sc[kS];
  size_t qrow = ((size_t)b * kS + qi) * kD + h * kDH;
  qsh[t] = bf2f(qo_in[qrow + t]);
  __syncthreads();
  const float scale = 0.125f;  // 1/sqrt(64)
  for (int k = t; k <= qi; k += 64) {
    const unsigned short* kr = kv + ((size_t)b * kS + k) * 512 + h * kDH;
    float dot = 0.f;
#pragma unroll
    for (int d = 0; d < kDH; d += 4) {
      ushort4 kk = *reinterpret_cast<const ushort4*>(kr + d);
      dot += qsh[d] * bf2f(kk.x) + qsh[d + 1] * bf2f(kk.y) +
             qsh[d + 2] * bf2f(kk.z) + qsh[d + 3] * bf2f(kk.w);
    }
    sc[k] = dot * scale;
  }
  __syncthreads();
  float mx = -INFINITY;
  for (int k = t; k <= qi; k += 64) mx = fmaxf(mx, sc[k]);
#pragma unroll
  for (int o = 32; o >= 1; o >>= 1) mx = fmaxf(mx, __shfl_xor(mx, o));
  float sum = 0.f;
  for (int k = t; k <= qi; k += 64) {
    float e = __expf(sc[k] - mx);
    sc[k] = e;
    sum += e;
  }
#pragma unroll
  for (int o = 32; o >= 1; o >>= 1) sum += __shfl_xor(sum, o);
  __syncthreads();
  float inv = 1.f / sum;
  float oacc = 0.f;
  for (int k = 0; k <= qi; ++k) {
    float p = sc[k];
    oacc += p * bf2f(kv[((size_t)b * kS + k) * 512 + 256 + h * kDH + t]);
  }
  qo_out[qrow + t] = f2bf(oacc * inv);
}

__global__ __launch_bounds__(64) void logits_kernel(
    const unsigned short* __restrict__ feats, const float* __restrict__ item_emb,
    const int* __restrict__ pos_seqs, const int* __restrict__ neg_seqs,
    float* __restrict__ out) {
  int bs = blockIdx.x;
  int t = threadIdx.x;
  ushort4 f4 = reinterpret_cast<const ushort4*>(feats + (size_t)bs * kD)[t];
  float fx = bf2f(f4.x), fy = bf2f(f4.y), fz = bf2f(f4.z), fw = bf2f(f4.w);
  int pi = pos_seqs[bs], ni = neg_seqs[bs];
  float4 p = reinterpret_cast<const float4*>(item_emb + (size_t)pi * kD)[t];
  float4 n = reinterpret_cast<const float4*>(item_emb + (size_t)ni * kD)[t];
  float dp = fx * p.x + fy * p.y + fz * p.z + fw * p.w;
  float dn = fx * n.x + fy * n.y + fz * n.z + fw * n.w;
#pragma unroll
  for (int o = 32; o >= 1; o >>= 1) {
    dp += __shfl_xor(dp, o);
    dn += __shfl_xor(dn, o);
  }
  if (t == 0) {
    out[bs] = dp;
    out[(size_t)kB * kS + bs] = dn;
  }
}

}  // namespace

extern "C" void kernel_launch(void* const* d_in, const int* in_sizes, int n_in,
                              void* d_out, int out_size, void* d_ws,
                              size_t ws_size, hipStream_t stream) {
  const float* item_emb = (const float*)d_in[0];
  const float* pos_emb  = (const float*)d_in[1];
  const float* ln1_g = (const float*)d_in[2];
  const float* ln1_b = (const float*)d_in[3];
  const float* in_w  = (const float*)d_in[4];   // [2,768,256]
  const float* in_b  = (const float*)d_in[5];   // [2,768]
  const float* out_w = (const float*)d_in[6];   // [2,256,256]
  const float* out_b = (const float*)d_in[7];
  const float* ln2_g = (const float*)d_in[8];
  const float* ln2_b = (const float*)d_in[9];
  const float* c1_w  = (const float*)d_in[10];
  const float* c1_b  = (const float*)d_in[11];
  const float* c2_w  = (const float*)d_in[12];
  const float* c2_b  = (const float*)d_in[13];
  const float* last_g = (const float*)d_in[14];
  const float* last_b = (const float*)d_in[15];
  // d_in[16] = user_ids (unused by reference)
  const int* log_seqs = (const int*)d_in[17];
  const int* pos_seqs = (const int*)d_in[18];
  const int* neg_seqs = (const int*)d_in[19];
  float* out = (float*)d_out;

  // 4 rotating units of kM*kD bf16 each (50 MiB): peak ws = 200 MiB.
  size_t unit = (size_t)kM * kD;
  unsigned short* U[4];
  U[0] = (unsigned short*)d_ws;
  U[1] = U[0] + unit;
  U[2] = U[0] + 2 * unit;
  U[3] = U[0] + 3 * unit;

  embed_kernel<<<kM, 64, 0, stream>>>(item_emb, pos_emb, log_seqs, U[0]);

  for (int i = 0; i < 2; ++i) {
    unsigned short* sin  = U[i == 0 ? 0 : 2];   // seqs in
    unsigned short* kvb  = U[i == 0 ? 2 : 0];   // k|v (2 contiguous units)
    unsigned short* Qb   = U[i == 0 ? 1 : 3];   // LN1 output
    unsigned short* qb   = sin;                  // q overwrites dead seqs
    unsigned short* sout = kvb;                  // new seqs overwrites dead kv
    unsigned short* h1b  = kvb + unit;           // h1 in second kv unit
    const float* iw = in_w + (size_t)i * 768 * kD;
    const float* ib = in_b + (size_t)i * 768;

    // k|v = seqs @ Wkv^T + bkv   (consume seqs for kv FIRST)
    gemm_kernel<0><<<dim3(kM / 64, 8), 256, 0, stream>>>(
        sin, iw + 256 * kD, ib + 256, nullptr, nullptr, kvb, 512);
    // Q = LN1(seqs)
    ln_kernel<<<kM, 64, 0, stream>>>(sin, ln1_g + i * kD, ln1_b + i * kD, Qb);
    // q = Q @ Wq^T + bq   (seqs dead -> reuse its unit)
    gemm_kernel<0><<<dim3(kM / 64, 4), 256, 0, stream>>>(
        Qb, iw, ib, nullptr, nullptr, qb, 256);
    attn_kernel<<<kB * kH * kS, 64, 0, stream>>>(qb, kvb, qb);
    // seqs' = Q + o @ out_w^T + out_b   (kv dead -> reuse)
    gemm_kernel<2><<<dim3(kM / 64, 4), 256, 0, stream>>>(
        qb, out_w + (size_t)i * kD * kD, out_b + i * kD, Qb, nullptr, sout, 256);
    ln_kernel<<<kM, 64, 0, stream>>>(sout, ln2_g + i * kD, ln2_b + i * kD, sout);
    // h1 = relu(seqs' @ c1^T + b1)
    gemm_kernel<1><<<dim3(kM / 64, 4), 256, 0, stream>>>(
        sout, c1_w + (size_t)i * kD * kD, c1_b + i * kD, nullptr, nullptr, h1b, 256);
    // seqs'' = (h1 @ c2^T + b2 + seqs') * mask
    gemm_kernel<3><<<dim3(kM / 64, 4), 256, 0, stream>>>(
        h1b, c2_w + (size_t)i * kD * kD, c2_b + i * kD, sout, log_seqs, sout, 256);
  }

  // final seqs is in U[0]; feats -> U[1]
  ln_kernel<<<kM, 64, 0, stream>>>(U[0], last_g, last_b, U[1]);
  logits_kernel<<<kM, 64, 0, stream>>>(U[1], item_emb, pos_seqs, neg_seqs, out);
}

// Round 3
// 949.491 us; speedup vs baseline: 6.2553x; 6.2553x over previous
//
#include <hip/hip_runtime.h>
#include <math.h>

namespace {

constexpr int kB = 512, kS = 200, kD = 256, kH = 4, kDH = 64;
constexpr int kM = kB * kS;           // 102400 rows
constexpr float kEps = 1e-8f;

typedef short bf16x8 __attribute__((ext_vector_type(8)));   // 8 bf16 = 4 VGPR
typedef float f32x4 __attribute__((ext_vector_type(4)));

__device__ __forceinline__ float bf2f(unsigned short s) {
  return __uint_as_float(((unsigned)s) << 16);
}
__device__ __forceinline__ unsigned short f2bf(float f) {
  unsigned u = __float_as_uint(f);
  return (unsigned short)((u + 0x7fffu + ((u >> 16) & 1u)) >> 16);
}

// ---------------- weights f32 -> bf16 ----------------
__global__ __launch_bounds__(256) void cvt_kernel(
    const float* __restrict__ src, unsigned short* __restrict__ dst, int n) {
  int i4 = (blockIdx.x * 256 + threadIdx.x) * 4;
  if (i4 >= n) return;
  float4 v = *reinterpret_cast<const float4*>(src + i4);
  ushort4 o = {f2bf(v.x), f2bf(v.y), f2bf(v.z), f2bf(v.w)};
  *reinterpret_cast<ushort4*>(dst + i4) = o;
}

// ---------------- embed ----------------
__global__ __launch_bounds__(64) void embed_kernel(
    const float* __restrict__ item_emb, const float* __restrict__ pos_emb,
    const int* __restrict__ log_seqs, unsigned short* __restrict__ seqs) {
  int bs = blockIdx.x;
  int s = bs % kS;
  int idx = log_seqs[bs];
  float msk = (idx != 0) ? 1.f : 0.f;
  int t = threadIdx.x;
  float4 a = reinterpret_cast<const float4*>(item_emb + (size_t)idx * kD)[t];
  float4 p = reinterpret_cast<const float4*>(pos_emb + (size_t)s * kD)[t];
  ushort4 r;
  r.x = f2bf((a.x * 16.f + p.x) * msk);
  r.y = f2bf((a.y * 16.f + p.y) * msk);
  r.z = f2bf((a.z * 16.f + p.z) * msk);
  r.w = f2bf((a.w * 16.f + p.w) * msk);
  reinterpret_cast<ushort4*>(seqs + (size_t)bs * kD)[t] = r;
}

// ---------------- layernorm (row=256) ----------------
__global__ __launch_bounds__(64) void ln_kernel(
    const unsigned short* __restrict__ x, const float* __restrict__ g,
    const float* __restrict__ b, unsigned short* __restrict__ y) {
  int row = blockIdx.x;
  int t = threadIdx.x;
  ushort4 v4 = reinterpret_cast<const ushort4*>(x + (size_t)row * kD)[t];
  float vx = bf2f(v4.x), vy = bf2f(v4.y), vz = bf2f(v4.z), vw = bf2f(v4.w);
  float sm = vx + vy + vz + vw;
#pragma unroll
  for (int o = 32; o >= 1; o >>= 1) sm += __shfl_xor(sm, o);
  float mean = sm * (1.f / kD);
  float dx = vx - mean, dy = vy - mean, dz = vz - mean, dw = vw - mean;
  float vs = dx * dx + dy * dy + dz * dz + dw * dw;
#pragma unroll
  for (int o = 32; o >= 1; o >>= 1) vs += __shfl_xor(vs, o);
  float inv = rsqrtf(vs * (1.f / kD) + kEps);
  float4 gg = reinterpret_cast<const float4*>(g)[t];
  float4 bb = reinterpret_cast<const float4*>(b)[t];
  ushort4 r;
  r.x = f2bf(dx * inv * gg.x + bb.x);
  r.y = f2bf(dy * inv * gg.y + bb.y);
  r.z = f2bf(dz * inv * gg.z + bb.z);
  r.w = f2bf(dw * inv * gg.w + bb.w);
  reinterpret_cast<ushort4*>(y + (size_t)row * kD)[t] = r;
}

// ---------------- MFMA GEMM ----------------
// C[M][N] = A[M][256] @ W[N][256]^T (+bias, +modes). A,W,C,R bf16; bias f32.
// Swapped operands: D[n][m] = sum_k W[n][k]*A[m][k]; A-op = W, B-op = A.
// MODE 0: +bias; 1: relu; 2: +bias+R; 3: (+bias+R)*mask
template <int MODE>
__global__ __launch_bounds__(256) void gemm_mfma(
    const unsigned short* __restrict__ A, const unsigned short* __restrict__ W,
    const float* __restrict__ bias, const unsigned short* __restrict__ R,
    const int* __restrict__ logseq, unsigned short* __restrict__ C, int N) {
  __shared__ __attribute__((aligned(16))) unsigned short As[128 * 72];
  __shared__ __attribute__((aligned(16))) unsigned short Ws[128 * 72];
  int m0 = blockIdx.x * 128, n0 = blockIdx.y * 128;
  int tid = threadIdx.x, lane = tid & 63, wid = tid >> 6;
  int wm = (wid & 1) * 64, wn = (wid >> 1) * 64;
  int lrow = lane & 15, lgrp = lane >> 4;
  f32x4 acc[4][4] = {};
  for (int k0 = 0; k0 < 256; k0 += 64) {
    if (k0) __syncthreads();
#pragma unroll
    for (int j = 0; j < 4; ++j) {
      int i = tid + j * 256;
      int row = i >> 3, c = i & 7;
      uint4 va = *reinterpret_cast<const uint4*>(A + (size_t)(m0 + row) * kD + k0 + c * 8);
      uint4 vw = *reinterpret_cast<const uint4*>(W + (size_t)(n0 + row) * kD + k0 + c * 8);
      *reinterpret_cast<uint4*>(&As[row * 72 + c * 8]) = va;
      *reinterpret_cast<uint4*>(&Ws[row * 72 + c * 8]) = vw;
    }
    __syncthreads();
#pragma unroll
    for (int kk = 0; kk < 2; ++kk) {
      bf16x8 af[4], bf[4];
#pragma unroll
      for (int x = 0; x < 4; ++x) {
        af[x] = *reinterpret_cast<const bf16x8*>(&Ws[(wn + x * 16 + lrow) * 72 + kk * 32 + lgrp * 8]);
        bf[x] = *reinterpret_cast<const bf16x8*>(&As[(wm + x * 16 + lrow) * 72 + kk * 32 + lgrp * 8]);
      }
#pragma unroll
      for (int na = 0; na < 4; ++na)
#pragma unroll
        for (int mb = 0; mb < 4; ++mb)
          acc[na][mb] = __builtin_amdgcn_mfma_f32_16x16x32_bf16(
              af[na], bf[mb], acc[na][mb], 0, 0, 0);
    }
  }
  // epilogue: lane holds n = n0+wn+na*16+lgrp*4+r (r=0..3 contiguous), m = m0+wm+mb*16+lrow
#pragma unroll
  for (int mb = 0; mb < 4; ++mb) {
    int m = m0 + wm + mb * 16 + lrow;
    float msk = 1.f;
    if (MODE == 3) msk = (logseq[m] != 0) ? 1.f : 0.f;
#pragma unroll
    for (int na = 0; na < 4; ++na) {
      int n4 = n0 + wn + na * 16 + lgrp * 4;
      float4 b4 = *reinterpret_cast<const float4*>(bias + n4);
      float bx[4] = {b4.x, b4.y, b4.z, b4.w};
      unsigned short rr[4] = {0, 0, 0, 0};
      if (MODE >= 2) {
        ushort4 rv = *reinterpret_cast<const ushort4*>(R + (size_t)m * N + n4);
        rr[0] = rv.x; rr[1] = rv.y; rr[2] = rv.z; rr[3] = rv.w;
      }
      ushort4 o;
      unsigned short* os = reinterpret_cast<unsigned short*>(&o);
#pragma unroll
      for (int r = 0; r < 4; ++r) {
        float v = acc[na][mb][r] + bx[r];
        if (MODE == 1) v = fmaxf(v, 0.f);
        if (MODE >= 2) v += bf2f(rr[r]);
        if (MODE == 3) v *= msk;
        os[r] = f2bf(v);
      }
      *reinterpret_cast<ushort4*>(C + (size_t)m * N + n4) = o;
    }
  }
}

// ---------------- MFMA flash attention ----------------
// One block per (b,h). K[200][64] row-major + V^T[64][200] staged in LDS.
// Swapped QK^T: S^T[key][q] = mfma(A=K, B=Q^T): lane column q = lane&15.
// PV: O^T[d][q] = mfma(A=Vt, B=P^T).
__global__ __launch_bounds__(256) void attn_mfma(
    const unsigned short* __restrict__ qbuf,
    const unsigned short* __restrict__ kv,
    unsigned short* __restrict__ obuf) {
  __shared__ __attribute__((aligned(16))) unsigned short Kl[200 * 72];
  __shared__ __attribute__((aligned(16))) unsigned short Vt[64 * 232];
  __shared__ __attribute__((aligned(16))) unsigned short Pt[4][16 * 40];
  int b = blockIdx.x >> 2, h = blockIdx.x & 3;
  int tid = threadIdx.x, lane = tid & 63, wid = tid >> 6;
  const unsigned short* kvb = kv + (size_t)b * kS * 512 + h * 64;
  // stage K (row-major, rows padded to 72)
  for (int i = tid; i < 1600; i += 256) {
    int row = i >> 3, c = i & 7;
    *reinterpret_cast<uint4*>(&Kl[row * 72 + c * 8]) =
        *reinterpret_cast<const uint4*>(kvb + (size_t)row * 512 + c * 8);
  }
  // stage V transposed: Vt[d][key], rows padded to 232
  for (int i = tid; i < 3200; i += 256) {
    int row = i >> 4, d0 = (i & 15) * 4;
    ushort4 v = *reinterpret_cast<const ushort4*>(kvb + 256 + (size_t)row * 512 + d0);
    Vt[(d0 + 0) * 232 + row] = v.x;
    Vt[(d0 + 1) * 232 + row] = v.y;
    Vt[(d0 + 2) * 232 + row] = v.z;
    Vt[(d0 + 3) * 232 + row] = v.w;
  }
  // zero tail cols 200..231 (read by last key-chunk; must be finite/zero)
  for (int i = tid; i < 2048; i += 256) {
    int d = i >> 5, c = i & 31;
    Vt[d * 232 + 200 + c] = 0;
  }
  __syncthreads();

  int qcol = lane & 15, kgrp = lane >> 4;
  // greedy-balanced causal tile assignment (13 tiles of 16 q-rows; nibble-packed)
  int packed = (wid < 2) ? (wid == 0 ? 0xF45C : 0xF37B)
                         : (wid == 2 ? 0xF26A : 0x0189);
  for (int ti = 0; ti < 4; ++ti) {
    int t = (packed >> (ti * 4)) & 15;
    if (t == 15) break;
    int qb = t * 16;
    int qrow = qb + qcol;
    int qm = min(qrow, kS - 1);
    const unsigned short* qrp = qbuf + (size_t)(b * kS + qm) * kD + h * 64;
    bf16x8 qf0 = *reinterpret_cast<const bf16x8*>(qrp + kgrp * 8);
    bf16x8 qf1 = *reinterpret_cast<const bf16x8*>(qrp + 32 + kgrp * 8);
    f32x4 accO[4] = {};
    float m_run = -3.0e38f, l_run = 0.f;
    int nc = (qb + 47) >> 5;
    for (int c = 0; c < nc; ++c) {
      int kbase = c * 32;
      f32x4 s0 = {}, s1 = {};
      int kr0 = min(kbase + qcol, kS - 1);
      int kr1 = min(kbase + 16 + qcol, kS - 1);
      const unsigned short* K0 = &Kl[kr0 * 72 + kgrp * 8];
      const unsigned short* K1 = &Kl[kr1 * 72 + kgrp * 8];
      s0 = __builtin_amdgcn_mfma_f32_16x16x32_bf16(*reinterpret_cast<const bf16x8*>(K0), qf0, s0, 0, 0, 0);
      s0 = __builtin_amdgcn_mfma_f32_16x16x32_bf16(*reinterpret_cast<const bf16x8*>(K0 + 32), qf1, s0, 0, 0, 0);
      s1 = __builtin_amdgcn_mfma_f32_16x16x32_bf16(*reinterpret_cast<const bf16x8*>(K1), qf0, s1, 0, 0, 0);
      s1 = __builtin_amdgcn_mfma_f32_16x16x32_bf16(*reinterpret_cast<const bf16x8*>(K1 + 32), qf1, s1, 0, 0, 0);
      // mask + scale; lane's 8 scores all belong to q-column (lane&15)
      float sv[8];
      float cm = -3.0e38f;
#pragma unroll
      for (int r = 0; r < 4; ++r) {
        int key0 = kbase + kgrp * 4 + r;
        int key1 = key0 + 16;
        float x0 = (key0 <= qm) ? s0[r] * 0.125f : -3.0e38f;
        float x1 = (key1 <= qm) ? s1[r] * 0.125f : -3.0e38f;
        sv[r] = x0; sv[r + 4] = x1;
        cm = fmaxf(cm, fmaxf(x0, x1));
      }
      cm = fmaxf(cm, __shfl_xor(cm, 16));
      cm = fmaxf(cm, __shfl_xor(cm, 32));
      float m_new = fmaxf(m_run, cm);
      float sc = __expf(m_run - m_new);
      float psum = 0.f;
      unsigned short pk[8];
#pragma unroll
      for (int r = 0; r < 8; ++r) {
        float p = __expf(sv[r] - m_new);
        psum += p;
        pk[r] = f2bf(p);
      }
      m_run = m_new;
      l_run = l_run * sc + psum;
#pragma unroll
      for (int nf = 0; nf < 4; ++nf) accO[nf] *= sc;
      ushort4 w0 = {pk[0], pk[1], pk[2], pk[3]};
      ushort4 w1 = {pk[4], pk[5], pk[6], pk[7]};
      *reinterpret_cast<ushort4*>(&Pt[wid][qcol * 40 + kgrp * 4]) = w0;
      *reinterpret_cast<ushort4*>(&Pt[wid][qcol * 40 + 16 + kgrp * 4]) = w1;
      // PV
      bf16x8 pf = *reinterpret_cast<const bf16x8*>(&Pt[wid][qcol * 40 + kgrp * 8]);
#pragma unroll
      for (int nf = 0; nf < 4; ++nf) {
        bf16x8 vf = *reinterpret_cast<const bf16x8*>(
            &Vt[(nf * 16 + qcol) * 232 + kbase + kgrp * 8]);
        accO[nf] = __builtin_amdgcn_mfma_f32_16x16x32_bf16(vf, pf, accO[nf], 0, 0, 0);
      }
    }
    float l_tot = l_run;
    l_tot += __shfl_xor(l_tot, 16);
    l_tot += __shfl_xor(l_tot, 32);
    float inv = 1.f / l_tot;
    if (qrow < kS) {
      unsigned short* op = obuf + (size_t)(b * kS + qrow) * kD + h * 64;
#pragma unroll
      for (int nf = 0; nf < 4; ++nf) {
        ushort4 o4 = {f2bf(accO[nf][0] * inv), f2bf(accO[nf][1] * inv),
                      f2bf(accO[nf][2] * inv), f2bf(accO[nf][3] * inv)};
        *reinterpret_cast<ushort4*>(op + nf * 16 + kgrp * 4) = o4;
      }
    }
  }
}

// ---------------- logits ----------------
__global__ __launch_bounds__(64) void logits_kernel(
    const unsigned short* __restrict__ feats, const float* __restrict__ item_emb,
    const int* __restrict__ pos_seqs, const int* __restrict__ neg_seqs,
    float* __restrict__ out) {
  int bs = blockIdx.x;
  int t = threadIdx.x;
  ushort4 f4 = reinterpret_cast<const ushort4*>(feats + (size_t)bs * kD)[t];
  float fx = bf2f(f4.x), fy = bf2f(f4.y), fz = bf2f(f4.z), fw = bf2f(f4.w);
  int pi = pos_seqs[bs], ni = neg_seqs[bs];
  float4 p = reinterpret_cast<const float4*>(item_emb + (size_t)pi * kD)[t];
  float4 n = reinterpret_cast<const float4*>(item_emb + (size_t)ni * kD)[t];
  float dp = fx * p.x + fy * p.y + fz * p.z + fw * p.w;
  float dn = fx * n.x + fy * n.y + fz * n.z + fw * n.w;
#pragma unroll
  for (int o = 32; o >= 1; o >>= 1) {
    dp += __shfl_xor(dp, o);
    dn += __shfl_xor(dn, o);
  }
  if (t == 0) {
    out[bs] = dp;
    out[(size_t)kB * kS + bs] = dn;
  }
}

}  // namespace

extern "C" void kernel_launch(void* const* d_in, const int* in_sizes, int n_in,
                              void* d_out, int out_size, void* d_ws,
                              size_t ws_size, hipStream_t stream) {
  const float* item_emb = (const float*)d_in[0];
  const float* pos_emb  = (const float*)d_in[1];
  const float* ln1_g = (const float*)d_in[2];
  const float* ln1_b = (const float*)d_in[3];
  const float* in_w  = (const float*)d_in[4];   // [2,768,256]
  const float* in_b  = (const float*)d_in[5];   // [2,768]
  const float* out_w = (const float*)d_in[6];   // [2,256,256]
  const float* out_b = (const float*)d_in[7];
  const float* ln2_g = (const float*)d_in[8];
  const float* ln2_b = (const float*)d_in[9];
  const float* c1_w  = (const float*)d_in[10];
  const float* c1_b  = (const float*)d_in[11];
  const float* c2_w  = (const float*)d_in[12];
  const float* c2_b  = (const float*)d_in[13];
  const float* last_g = (const float*)d_in[14];
  const float* last_b = (const float*)d_in[15];
  const int* log_seqs = (const int*)d_in[17];
  const int* pos_seqs = (const int*)d_in[18];
  const int* neg_seqs = (const int*)d_in[19];
  float* out = (float*)d_out;

  // 4 rotating activation units (bf16, 50 MiB each) + bf16 weights tail
  size_t unit = (size_t)kM * kD;
  unsigned short* U0 = (unsigned short*)d_ws;
  unsigned short* U[4] = {U0, U0 + unit, U0 + 2 * unit, U0 + 3 * unit};
  unsigned short* inw_bf  = U0 + 4 * unit;            // 2*768*256
  unsigned short* outw_bf = inw_bf + 2 * 768 * 256;   // 2*256*256
  unsigned short* c1w_bf  = outw_bf + 2 * 256 * 256;
  unsigned short* c2w_bf  = c1w_bf + 2 * 256 * 256;

  cvt_kernel<<<2 * 768 * 256 / 1024, 256, 0, stream>>>(in_w, inw_bf, 2 * 768 * 256);
  cvt_kernel<<<2 * 256 * 256 / 1024, 256, 0, stream>>>(out_w, outw_bf, 2 * 256 * 256);
  cvt_kernel<<<2 * 256 * 256 / 1024, 256, 0, stream>>>(c1_w, c1w_bf, 2 * 256 * 256);
  cvt_kernel<<<2 * 256 * 256 / 1024, 256, 0, stream>>>(c2_w, c2w_bf, 2 * 256 * 256);

  embed_kernel<<<kM, 64, 0, stream>>>(item_emb, pos_emb, log_seqs, U[0]);

  for (int i = 0; i < 2; ++i) {
    unsigned short* sin  = U[i == 0 ? 0 : 2];   // seqs in
    unsigned short* kvb  = U[i == 0 ? 2 : 0];   // k|v (2 contiguous units)
    unsigned short* Qb   = U[i == 0 ? 1 : 3];   // LN1 output
    unsigned short* qb   = sin;                  // q overwrites dead seqs
    unsigned short* sout = kvb;                  // new seqs overwrites dead kv
    unsigned short* h1b  = kvb + unit;           // h1 in second kv unit
    const unsigned short* iw = inw_bf + (size_t)i * 768 * kD;
    const float* ib = in_b + (size_t)i * 768;

    gemm_mfma<0><<<dim3(kM / 128, 4), 256, 0, stream>>>(
        sin, iw + 256 * kD, ib + 256, nullptr, nullptr, kvb, 512);
    ln_kernel<<<kM, 64, 0, stream>>>(sin, ln1_g + i * kD, ln1_b + i * kD, Qb);
    gemm_mfma<0><<<dim3(kM / 128, 2), 256, 0, stream>>>(
        Qb, iw, ib, nullptr, nullptr, qb, 256);
    attn_mfma<<<kB * kH, 256, 0, stream>>>(qb, kvb, qb);
    gemm_mfma<2><<<dim3(kM / 128, 2), 256, 0, stream>>>(
        qb, outw_bf + (size_t)i * kD * kD, out_b + i * kD, Qb, nullptr, sout, 256);
    ln_kernel<<<kM, 64, 0, stream>>>(sout, ln2_g + i * kD, ln2_b + i * kD, sout);
    gemm_mfma<1><<<dim3(kM / 128, 2), 256, 0, stream>>>(
        sout, c1w_bf + (size_t)i * kD * kD, c1_b + i * kD, nullptr, nullptr, h1b, 256);
    gemm_mfma<3><<<dim3(kM / 128, 2), 256, 0, stream>>>(
        h1b, c2w_bf + (size_t)i * kD * kD, c2_b + i * kD, sout, log_seqs, sout, 256);
  }

  ln_kernel<<<kM, 64, 0, stream>>>(U[0], last_g, last_b, U[1]);
  logits_kernel<<<kM, 64, 0, stream>>>(U[1], item_emb, pos_seqs, neg_seqs, out);
}

// Round 4
// 831.470 us; speedup vs baseline: 7.1432x; 1.1419x over previous
//
#include <hip/hip_runtime.h>
#include <math.h>

namespace {

constexpr int kB = 512, kS = 200, kD = 256, kH = 4, kDH = 64;
constexpr int kM = kB * kS;           // 102400 rows
constexpr float kEps = 1e-8f;

typedef short bf16x8 __attribute__((ext_vector_type(8)));   // 8 bf16 = 4 VGPR
typedef float f32x4 __attribute__((ext_vector_type(4)));

__device__ __forceinline__ float bf2f(unsigned short s) {
  return __uint_as_float(((unsigned)s) << 16);
}
__device__ __forceinline__ unsigned short f2bf(float f) {
  unsigned u = __float_as_uint(f);
  return (unsigned short)((u + 0x7fffu + ((u >> 16) & 1u)) >> 16);
}
// async global->LDS, 16B per lane; lds dst is wave-uniform base (HW adds lane*16)
__device__ __forceinline__ void gload16(const void* g, void* l) {
  __builtin_amdgcn_global_load_lds(
      (const __attribute__((address_space(1))) void*)g,
      (__attribute__((address_space(3))) void*)l, 16, 0, 0);
}

// ---------------- weights f32 -> bf16 ----------------
__global__ __launch_bounds__(256) void cvt_kernel(
    const float* __restrict__ src, unsigned short* __restrict__ dst, int n) {
  int i4 = (blockIdx.x * 256 + threadIdx.x) * 4;
  if (i4 >= n) return;
  float4 v = *reinterpret_cast<const float4*>(src + i4);
  ushort4 o = {f2bf(v.x), f2bf(v.y), f2bf(v.z), f2bf(v.w)};
  *reinterpret_cast<ushort4*>(dst + i4) = o;
}

// ---------------- embed + fused LN1(layer0) ----------------
__global__ __launch_bounds__(64) void embed_ln_kernel(
    const float* __restrict__ item_emb, const float* __restrict__ pos_emb,
    const int* __restrict__ log_seqs, const float* __restrict__ g,
    const float* __restrict__ b, unsigned short* __restrict__ seqs,
    unsigned short* __restrict__ q) {
  int bs = blockIdx.x;
  int s = bs % kS;
  int idx = log_seqs[bs];
  float msk = (idx != 0) ? 1.f : 0.f;
  int t = threadIdx.x;
  float4 a = reinterpret_cast<const float4*>(item_emb + (size_t)idx * kD)[t];
  float4 p = reinterpret_cast<const float4*>(pos_emb + (size_t)s * kD)[t];
  float v[4];
  v[0] = (a.x * 16.f + p.x) * msk;
  v[1] = (a.y * 16.f + p.y) * msk;
  v[2] = (a.z * 16.f + p.z) * msk;
  v[3] = (a.w * 16.f + p.w) * msk;
  ushort4 r = {f2bf(v[0]), f2bf(v[1]), f2bf(v[2]), f2bf(v[3])};
  reinterpret_cast<ushort4*>(seqs + (size_t)bs * kD)[t] = r;
  float sm = v[0] + v[1] + v[2] + v[3];
#pragma unroll
  for (int o = 32; o >= 1; o >>= 1) sm += __shfl_xor(sm, o);
  float mean = sm * (1.f / kD);
  float d0 = v[0] - mean, d1 = v[1] - mean, d2 = v[2] - mean, d3 = v[3] - mean;
  float vs = d0 * d0 + d1 * d1 + d2 * d2 + d3 * d3;
#pragma unroll
  for (int o = 32; o >= 1; o >>= 1) vs += __shfl_xor(vs, o);
  float inv = rsqrtf(vs * (1.f / kD) + kEps);
  float4 gg = reinterpret_cast<const float4*>(g)[t];
  float4 bb = reinterpret_cast<const float4*>(b)[t];
  ushort4 rq = {f2bf(d0 * inv * gg.x + bb.x), f2bf(d1 * inv * gg.y + bb.y),
                f2bf(d2 * inv * gg.z + bb.z), f2bf(d3 * inv * gg.w + bb.w)};
  reinterpret_cast<ushort4*>(q + (size_t)bs * kD)[t] = rq;
}

// ---------------- fused MFMA GEMM ----------------
// C[M][N] = A[M][256] @ W[N][256]^T + bias (+modes) with optional fused row-LN.
// Tile 128m x 256n, 8 waves (2m x 4n), BK=64, global_load_lds staging.
// MODE: 0 plain, 1 relu, 2 +R, 3 +R then *mask
// LN:   0 none, 1 write LN(v) to C, 2 write v to C and LN(v) to C2
template <int MODE, int LN>
__global__ __launch_bounds__(512) void gemm_fused(
    const unsigned short* __restrict__ A, const unsigned short* __restrict__ W,
    const float* __restrict__ bias, const unsigned short* __restrict__ R,
    const int* __restrict__ logseq, const float* __restrict__ lng,
    const float* __restrict__ lnb, unsigned short* __restrict__ C,
    unsigned short* __restrict__ C2, int N) {
  __shared__ __attribute__((aligned(16))) unsigned short As[128 * 64];
  __shared__ __attribute__((aligned(16))) unsigned short Ws[256 * 64];
  __shared__ float red1[128][4];
  __shared__ float red2[128][4];
  const int tid = threadIdx.x, lane = tid & 63, wid = tid >> 6;
  const int m0 = blockIdx.x * 128, n0 = blockIdx.y * 256;
  const int wm = wid >> 2, wn = wid & 3;
  const int lrow = lane & 15, kgrp = lane >> 4;
  // staging source pointers (per-lane global), dst uniform per wave
  const int arow = wid * 16 + (lane >> 3);           // + j*8 rows
  const int wrow = wid * 32 + (lane >> 3);
  const unsigned short* gA = A + (size_t)(m0 + arow) * kD + (lane & 7) * 8;
  const unsigned short* gW = W + (size_t)(n0 + wrow) * kD + (lane & 7) * 8;
  unsigned short* lA = &As[wid * 1024];
  unsigned short* lW = &Ws[wid * 2048];
  f32x4 acc[4][4] = {};
  for (int k0 = 0; k0 < kD; k0 += 64) {
    gload16(gA + k0, lA);
    gload16(gA + k0 + 8 * kD, lA + 512);
    gload16(gW + k0, lW);
    gload16(gW + k0 + 8 * kD, lW + 512);
    gload16(gW + k0 + 16 * kD, lW + 1024);
    gload16(gW + k0 + 24 * kD, lW + 1536);
    asm volatile("s_waitcnt vmcnt(0)" ::: "memory");
    __syncthreads();
#pragma unroll
    for (int kk = 0; kk < 2; ++kk) {
      bf16x8 af[4], bfr[4];
#pragma unroll
      for (int x = 0; x < 4; ++x) {
        af[x]  = *reinterpret_cast<const bf16x8*>(&Ws[(wn * 64 + x * 16 + lrow) * 64 + kk * 32 + kgrp * 8]);
        bfr[x] = *reinterpret_cast<const bf16x8*>(&As[(wm * 64 + x * 16 + lrow) * 64 + kk * 32 + kgrp * 8]);
      }
#pragma unroll
      for (int na = 0; na < 4; ++na)
#pragma unroll
        for (int mb = 0; mb < 4; ++mb)
          acc[na][mb] = __builtin_amdgcn_mfma_f32_16x16x32_bf16(
              af[na], bfr[mb], acc[na][mb], 0, 0, 0);
    }
    __syncthreads();
  }
  // ---- epilogue: v = acc + bias (+R) (relu) (*mask); LN partials ----
  float msk[4];
  if (MODE == 3) {
#pragma unroll
    for (int mb = 0; mb < 4; ++mb)
      msk[mb] = (logseq[m0 + wm * 64 + mb * 16 + lrow] != 0) ? 1.f : 0.f;
  }
  float s1[4] = {0.f, 0.f, 0.f, 0.f}, s2[4] = {0.f, 0.f, 0.f, 0.f};
#pragma unroll
  for (int na = 0; na < 4; ++na) {
    int gcol = n0 + wn * 64 + na * 16 + kgrp * 4;
    float4 b4 = *reinterpret_cast<const float4*>(bias + gcol);
    float bx[4] = {b4.x, b4.y, b4.z, b4.w};
#pragma unroll
    for (int mb = 0; mb < 4; ++mb) {
      int m = m0 + wm * 64 + mb * 16 + lrow;
      f32x4 v = acc[na][mb];
      ushort4 rv;
      if (MODE >= 2)
        rv = *reinterpret_cast<const ushort4*>(R + (size_t)m * N + gcol);
#pragma unroll
      for (int r = 0; r < 4; ++r) {
        float x = v[r] + bx[r];
        if (MODE == 1) x = fmaxf(x, 0.f);
        if (MODE >= 2) x += bf2f(reinterpret_cast<const unsigned short*>(&rv)[r]);
        if (MODE == 3) x *= msk[mb];
        v[r] = x;
        if (LN) { s1[mb] += x; s2[mb] += x * x; }
      }
      acc[na][mb] = v;
    }
  }
  float mean[4], inv[4];
  if (LN) {
#pragma unroll
    for (int mb = 0; mb < 4; ++mb) {
      s1[mb] += __shfl_xor(s1[mb], 16); s1[mb] += __shfl_xor(s1[mb], 32);
      s2[mb] += __shfl_xor(s2[mb], 16); s2[mb] += __shfl_xor(s2[mb], 32);
    }
    if (kgrp == 0) {
#pragma unroll
      for (int mb = 0; mb < 4; ++mb) {
        int rl = wm * 64 + mb * 16 + lrow;
        red1[rl][wn] = s1[mb];
        red2[rl][wn] = s2[mb];
      }
    }
    __syncthreads();
#pragma unroll
    for (int mb = 0; mb < 4; ++mb) {
      int rl = wm * 64 + mb * 16 + lrow;
      float4 p1 = *reinterpret_cast<const float4*>(red1[rl]);
      float4 p2 = *reinterpret_cast<const float4*>(red2[rl]);
      float t1 = p1.x + p1.y + p1.z + p1.w;
      float t2 = p2.x + p2.y + p2.z + p2.w;
      float mu = t1 * (1.f / 256.f);
      float var = t2 * (1.f / 256.f) - mu * mu;
      mean[mb] = mu;
      inv[mb] = rsqrtf(fmaxf(var, 0.f) + kEps);
    }
  }
#pragma unroll
  for (int na = 0; na < 4; ++na) {
    int gcol = n0 + wn * 64 + na * 16 + kgrp * 4;
    float gg[4], lb[4];
    if (LN) {
      float4 g4 = *reinterpret_cast<const float4*>(lng + gcol);
      float4 b4 = *reinterpret_cast<const float4*>(lnb + gcol);
      gg[0] = g4.x; gg[1] = g4.y; gg[2] = g4.z; gg[3] = g4.w;
      lb[0] = b4.x; lb[1] = b4.y; lb[2] = b4.z; lb[3] = b4.w;
    }
#pragma unroll
    for (int mb = 0; mb < 4; ++mb) {
      int m = m0 + wm * 64 + mb * 16 + lrow;
      f32x4 v = acc[na][mb];
      if (LN == 2 || LN == 0) {
        ushort4 o = {f2bf(v[0]), f2bf(v[1]), f2bf(v[2]), f2bf(v[3])};
        *reinterpret_cast<ushort4*>(C + (size_t)m * N + gcol) = o;
      }
      if (LN) {
        ushort4 o;
        unsigned short* os = reinterpret_cast<unsigned short*>(&o);
#pragma unroll
        for (int r = 0; r < 4; ++r)
          os[r] = f2bf((v[r] - mean[mb]) * inv[mb] * gg[r] + lb[r]);
        unsigned short* dst = (LN == 2) ? C2 : C;
        *reinterpret_cast<ushort4*>(dst + (size_t)m * 256 + gcol) = o;
      }
    }
  }
}

// ---------------- MFMA flash attention ----------------
// One block per (b,h). K[200][64] + V^T staged in LDS.
// Swapped QK^T: S^T[key][q] = mfma(A=K, B=Q^T); PV: O^T[d][q] = mfma(A=Vt, B=P^T).
__global__ __launch_bounds__(256) void attn_mfma(
    const unsigned short* __restrict__ qbuf,
    const unsigned short* __restrict__ kv,
    unsigned short* __restrict__ obuf) {
  __shared__ __attribute__((aligned(16))) unsigned short Kl[200 * 72];
  __shared__ __attribute__((aligned(16))) unsigned short Vt[64 * 232];
  __shared__ __attribute__((aligned(16))) unsigned short Pt[4][16 * 40];
  int b = blockIdx.x >> 2, h = blockIdx.x & 3;
  int tid = threadIdx.x, lane = tid & 63, wid = tid >> 6;
  const unsigned short* kvb = kv + (size_t)b * kS * 512 + h * 64;
  for (int i = tid; i < 1600; i += 256) {
    int row = i >> 3, c = i & 7;
    *reinterpret_cast<uint4*>(&Kl[row * 72 + c * 8]) =
        *reinterpret_cast<const uint4*>(kvb + (size_t)row * 512 + c * 8);
  }
  for (int i = tid; i < 3200; i += 256) {
    int row = i >> 4, d0 = (i & 15) * 4;
    ushort4 v = *reinterpret_cast<const ushort4*>(kvb + 256 + (size_t)row * 512 + d0);
    Vt[(d0 + 0) * 232 + row] = v.x;
    Vt[(d0 + 1) * 232 + row] = v.y;
    Vt[(d0 + 2) * 232 + row] = v.z;
    Vt[(d0 + 3) * 232 + row] = v.w;
  }
  for (int i = tid; i < 2048; i += 256) {
    int d = i >> 5, c = i & 31;
    Vt[d * 232 + 200 + c] = 0;
  }
  __syncthreads();

  int qcol = lane & 15, kgrp = lane >> 4;
  const float scale2 = 0.18033688f;  // (1/8) * log2(e)
  int packed = (wid < 2) ? (wid == 0 ? 0xF45C : 0xF37B)
                         : (wid == 2 ? 0xF26A : 0x0189);
  for (int ti = 0; ti < 4; ++ti) {
    int t = (packed >> (ti * 4)) & 15;
    if (t == 15) break;
    int qb = t * 16;
    int qrow = qb + qcol;
    int qm = min(qrow, kS - 1);
    const unsigned short* qrp = qbuf + (size_t)(b * kS + qm) * kD + h * 64;
    bf16x8 qf0 = *reinterpret_cast<const bf16x8*>(qrp + kgrp * 8);
    bf16x8 qf1 = *reinterpret_cast<const bf16x8*>(qrp + 32 + kgrp * 8);
    f32x4 accO[4] = {};
    float m_run = -3.0e38f, l_run = 0.f;
    int nc = (qb + 47) >> 5;
    for (int c = 0; c < nc; ++c) {
      int kbase = c * 32;
      f32x4 s0 = {}, s1 = {};
      int kr0 = min(kbase + qcol, kS - 1);
      int kr1 = min(kbase + 16 + qcol, kS - 1);
      const unsigned short* K0 = &Kl[kr0 * 72 + kgrp * 8];
      const unsigned short* K1 = &Kl[kr1 * 72 + kgrp * 8];
      s0 = __builtin_amdgcn_mfma_f32_16x16x32_bf16(*reinterpret_cast<const bf16x8*>(K0), qf0, s0, 0, 0, 0);
      s0 = __builtin_amdgcn_mfma_f32_16x16x32_bf16(*reinterpret_cast<const bf16x8*>(K0 + 32), qf1, s0, 0, 0, 0);
      s1 = __builtin_amdgcn_mfma_f32_16x16x32_bf16(*reinterpret_cast<const bf16x8*>(K1), qf0, s1, 0, 0, 0);
      s1 = __builtin_amdgcn_mfma_f32_16x16x32_bf16(*reinterpret_cast<const bf16x8*>(K1 + 32), qf1, s1, 0, 0, 0);
      float sv[8];
      float cm = -3.0e38f;
#pragma unroll
      for (int r = 0; r < 4; ++r) {
        int key0 = kbase + kgrp * 4 + r;
        int key1 = key0 + 16;
        float x0 = (key0 <= qm) ? s0[r] * scale2 : -3.0e38f;
        float x1 = (key1 <= qm) ? s1[r] * scale2 : -3.0e38f;
        sv[r] = x0; sv[r + 4] = x1;
        cm = fmaxf(cm, fmaxf(x0, x1));
      }
      cm = fmaxf(cm, __shfl_xor(cm, 16));
      cm = fmaxf(cm, __shfl_xor(cm, 32));
      float m_new = fmaxf(m_run, cm);
      float sc = exp2f(m_run - m_new);
      float psum = 0.f;
      unsigned short pk[8];
#pragma unroll
      for (int r = 0; r < 8; ++r) {
        float p = exp2f(sv[r] - m_new);
        psum += p;
        pk[r] = f2bf(p);
      }
      m_run = m_new;
      l_run = l_run * sc + psum;
#pragma unroll
      for (int nf = 0; nf < 4; ++nf) accO[nf] *= sc;
      ushort4 w0 = {pk[0], pk[1], pk[2], pk[3]};
      ushort4 w1 = {pk[4], pk[5], pk[6], pk[7]};
      *reinterpret_cast<ushort4*>(&Pt[wid][qcol * 40 + kgrp * 4]) = w0;
      *reinterpret_cast<ushort4*>(&Pt[wid][qcol * 40 + 16 + kgrp * 4]) = w1;
      bf16x8 pf = *reinterpret_cast<const bf16x8*>(&Pt[wid][qcol * 40 + kgrp * 8]);
#pragma unroll
      for (int nf = 0; nf < 4; ++nf) {
        bf16x8 vf = *reinterpret_cast<const bf16x8*>(
            &Vt[(nf * 16 + qcol) * 232 + kbase + kgrp * 8]);
        accO[nf] = __builtin_amdgcn_mfma_f32_16x16x32_bf16(vf, pf, accO[nf], 0, 0, 0);
      }
    }
    float l_tot = l_run;
    l_tot += __shfl_xor(l_tot, 16);
    l_tot += __shfl_xor(l_tot, 32);
    float inv = 1.f / l_tot;
    if (qrow < kS) {
      unsigned short* op = obuf + (size_t)(b * kS + qrow) * kD + h * 64;
#pragma unroll
      for (int nf = 0; nf < 4; ++nf) {
        ushort4 o4 = {f2bf(accO[nf][0] * inv), f2bf(accO[nf][1] * inv),
                      f2bf(accO[nf][2] * inv), f2bf(accO[nf][3] * inv)};
        *reinterpret_cast<ushort4*>(op + nf * 16 + kgrp * 4) = o4;
      }
    }
  }
}

// ---------------- logits ----------------
__global__ __launch_bounds__(64) void logits_kernel(
    const unsigned short* __restrict__ feats, const float* __restrict__ item_emb,
    const int* __restrict__ pos_seqs, const int* __restrict__ neg_seqs,
    float* __restrict__ out) {
  int bs = blockIdx.x;
  int t = threadIdx.x;
  ushort4 f4 = reinterpret_cast<const ushort4*>(feats + (size_t)bs * kD)[t];
  float fx = bf2f(f4.x), fy = bf2f(f4.y), fz = bf2f(f4.z), fw = bf2f(f4.w);
  int pi = pos_seqs[bs], ni = neg_seqs[bs];
  float4 p = reinterpret_cast<const float4*>(item_emb + (size_t)pi * kD)[t];
  float4 n = reinterpret_cast<const float4*>(item_emb + (size_t)ni * kD)[t];
  float dp = fx * p.x + fy * p.y + fz * p.z + fw * p.w;
  float dn = fx * n.x + fy * n.y + fz * n.z + fw * n.w;
#pragma unroll
  for (int o = 32; o >= 1; o >>= 1) {
    dp += __shfl_xor(dp, o);
    dn += __shfl_xor(dn, o);
  }
  if (t == 0) {
    out[bs] = dp;
    out[(size_t)kB * kS + bs] = dn;
  }
}

}  // namespace

extern "C" void kernel_launch(void* const* d_in, const int* in_sizes, int n_in,
                              void* d_out, int out_size, void* d_ws,
                              size_t ws_size, hipStream_t stream) {
  const float* item_emb = (const float*)d_in[0];
  const float* pos_emb  = (const float*)d_in[1];
  const float* ln1_g = (const float*)d_in[2];
  const float* ln1_b = (const float*)d_in[3];
  const float* in_w  = (const float*)d_in[4];   // [2,768,256]
  const float* in_b  = (const float*)d_in[5];   // [2,768]
  const float* out_w = (const float*)d_in[6];   // [2,256,256]
  const float* out_b = (const float*)d_in[7];
  const float* ln2_g = (const float*)d_in[8];
  const float* ln2_b = (const float*)d_in[9];
  const float* c1_w  = (const float*)d_in[10];
  const float* c1_b  = (const float*)d_in[11];
  const float* c2_w  = (const float*)d_in[12];
  const float* c2_b  = (const float*)d_in[13];
  const float* last_g = (const float*)d_in[14];
  const float* last_b = (const float*)d_in[15];
  const int* log_seqs = (const int*)d_in[17];
  const int* pos_seqs = (const int*)d_in[18];
  const int* neg_seqs = (const int*)d_in[19];
  float* out = (float*)d_out;

  size_t unit = (size_t)kM * kD;
  unsigned short* U0 = (unsigned short*)d_ws;
  unsigned short* U[4] = {U0, U0 + unit, U0 + 2 * unit, U0 + 3 * unit};
  unsigned short* inw_bf  = U0 + 4 * unit;
  unsigned short* outw_bf = inw_bf + 2 * 768 * 256;
  unsigned short* c1w_bf  = outw_bf + 2 * 256 * 256;
  unsigned short* c2w_bf  = c1w_bf + 2 * 256 * 256;

  cvt_kernel<<<2 * 768 * 256 / 1024, 256, 0, stream>>>(in_w, inw_bf, 2 * 768 * 256);
  cvt_kernel<<<2 * 256 * 256 / 1024, 256, 0, stream>>>(out_w, outw_bf, 2 * 256 * 256);
  cvt_kernel<<<2 * 256 * 256 / 1024, 256, 0, stream>>>(c1_w, c1w_bf, 2 * 256 * 256);
  cvt_kernel<<<2 * 256 * 256 / 1024, 256, 0, stream>>>(c2_w, c2w_bf, 2 * 256 * 256);

  // U0 = seqs0, U1 = Q0 (LN1 fused)
  embed_ln_kernel<<<kM, 64, 0, stream>>>(item_emb, pos_emb, log_seqs,
                                         ln1_g, ln1_b, U[0], U[1]);

  dim3 g1(kM / 128, 1), g2(kM / 128, 2);
  // ---- layer 0 ----
  const unsigned short* iw0 = inw_bf;
  gemm_fused<0, 0><<<g2, 512, 0, stream>>>(U[0], iw0 + 256 * kD, in_b + 256,
      nullptr, nullptr, nullptr, nullptr, U[2], nullptr, 512);           // kv -> U2|U3
  gemm_fused<0, 0><<<g1, 512, 0, stream>>>(U[1], iw0, in_b,
      nullptr, nullptr, nullptr, nullptr, U[0], nullptr, 256);           // q -> U0
  attn_mfma<<<kB * kH, 256, 0, stream>>>(U[0], U[2], U[0]);              // o -> U0
  gemm_fused<2, 1><<<g1, 512, 0, stream>>>(U[0], outw_bf, out_b,
      U[1], nullptr, ln2_g, ln2_b, U[1], nullptr, 256);                  // ln2 -> U1
  gemm_fused<1, 0><<<g1, 512, 0, stream>>>(U[1], c1w_bf, c1_b,
      nullptr, nullptr, nullptr, nullptr, U[0], nullptr, 256);           // h1 -> U0
  gemm_fused<3, 2><<<g1, 512, 0, stream>>>(U[0], c2w_bf, c2_b,
      U[1], log_seqs, ln1_g + 256, ln1_b + 256, U[2], U[3], 256);        // seqs1->U2, Q1->U3
  // ---- layer 1 ----
  const unsigned short* iw1 = inw_bf + (size_t)768 * 256;
  gemm_fused<0, 0><<<g2, 512, 0, stream>>>(U[2], iw1 + 256 * kD, in_b + 768 + 256,
      nullptr, nullptr, nullptr, nullptr, U[0], nullptr, 512);           // kv -> U0|U1
  gemm_fused<0, 0><<<g1, 512, 0, stream>>>(U[3], iw1, in_b + 768,
      nullptr, nullptr, nullptr, nullptr, U[2], nullptr, 256);           // q -> U2
  attn_mfma<<<kB * kH, 256, 0, stream>>>(U[2], U[0], U[2]);              // o -> U2
  gemm_fused<2, 1><<<g1, 512, 0, stream>>>(U[2], outw_bf + 256 * 256, out_b + 256,
      U[3], nullptr, ln2_g + 256, ln2_b + 256, U[3], nullptr, 256);      // ln2 -> U3
  gemm_fused<1, 0><<<g1, 512, 0, stream>>>(U[3], c1w_bf + 256 * 256, c1_b + 256,
      nullptr, nullptr, nullptr, nullptr, U[2], nullptr, 256);           // h1 -> U2
  gemm_fused<3, 1><<<g1, 512, 0, stream>>>(U[2], c2w_bf + 256 * 256, c2_b + 256,
      U[3], log_seqs, last_g, last_b, U[0], nullptr, 256);               // feats -> U0

  logits_kernel<<<kM, 64, 0, stream>>>(U[0], item_emb, pos_seqs, neg_seqs, out);
}

// Round 5
// 788.532 us; speedup vs baseline: 7.5321x; 1.0545x over previous
//
#include <hip/hip_runtime.h>
#include <math.h>

namespace {

constexpr int kB = 512, kS = 200, kD = 256, kH = 4, kDH = 64;
constexpr int kM = kB * kS;           // 102400 rows
constexpr float kEps = 1e-8f;

typedef short bf16x8 __attribute__((ext_vector_type(8)));   // 8 bf16 = 4 VGPR
typedef float f32x4 __attribute__((ext_vector_type(4)));

__device__ __forceinline__ float bf2f(unsigned short s) {
  return __uint_as_float(((unsigned)s) << 16);
}
__device__ __forceinline__ unsigned short f2bf(float f) {
  unsigned u = __float_as_uint(f);
  return (unsigned short)((u + 0x7fffu + ((u >> 16) & 1u)) >> 16);
}
__device__ __forceinline__ void gload16(const void* g, void* l) {
  __builtin_amdgcn_global_load_lds(
      (const __attribute__((address_space(1))) void*)g,
      (__attribute__((address_space(3))) void*)l, 16, 0, 0);
}
__device__ __forceinline__ void vm6() { asm volatile("s_waitcnt vmcnt(6)" ::: "memory"); }
__device__ __forceinline__ void vm3() { asm volatile("s_waitcnt vmcnt(3)" ::: "memory"); }
__device__ __forceinline__ void vm0() { asm volatile("s_waitcnt vmcnt(0)" ::: "memory"); }
__device__ __forceinline__ void bar() { asm volatile("s_barrier" ::: "memory"); }

// ---------------- weights f32 -> bf16 ----------------
__global__ __launch_bounds__(256) void cvt_kernel(
    const float* __restrict__ src, unsigned short* __restrict__ dst, int n) {
  int i4 = (blockIdx.x * 256 + threadIdx.x) * 4;
  if (i4 >= n) return;
  float4 v = *reinterpret_cast<const float4*>(src + i4);
  ushort4 o = {f2bf(v.x), f2bf(v.y), f2bf(v.z), f2bf(v.w)};
  *reinterpret_cast<ushort4*>(dst + i4) = o;
}

// ---------------- embed + fused LN1(layer0) ----------------
__global__ __launch_bounds__(64) void embed_ln_kernel(
    const float* __restrict__ item_emb, const float* __restrict__ pos_emb,
    const int* __restrict__ log_seqs, const float* __restrict__ g,
    const float* __restrict__ b, unsigned short* __restrict__ seqs,
    unsigned short* __restrict__ q) {
  int bs = blockIdx.x;
  int s = bs % kS;
  int idx = log_seqs[bs];
  float msk = (idx != 0) ? 1.f : 0.f;
  int t = threadIdx.x;
  float4 a = reinterpret_cast<const float4*>(item_emb + (size_t)idx * kD)[t];
  float4 p = reinterpret_cast<const float4*>(pos_emb + (size_t)s * kD)[t];
  float v[4];
  v[0] = (a.x * 16.f + p.x) * msk;
  v[1] = (a.y * 16.f + p.y) * msk;
  v[2] = (a.z * 16.f + p.z) * msk;
  v[3] = (a.w * 16.f + p.w) * msk;
  ushort4 r = {f2bf(v[0]), f2bf(v[1]), f2bf(v[2]), f2bf(v[3])};
  reinterpret_cast<ushort4*>(seqs + (size_t)bs * kD)[t] = r;
  float sm = v[0] + v[1] + v[2] + v[3];
#pragma unroll
  for (int o = 32; o >= 1; o >>= 1) sm += __shfl_xor(sm, o);
  float mean = sm * (1.f / kD);
  float d0 = v[0] - mean, d1 = v[1] - mean, d2 = v[2] - mean, d3 = v[3] - mean;
  float vs = d0 * d0 + d1 * d1 + d2 * d2 + d3 * d3;
#pragma unroll
  for (int o = 32; o >= 1; o >>= 1) vs += __shfl_xor(vs, o);
  float inv = rsqrtf(vs * (1.f / kD) + kEps);
  float4 gg = reinterpret_cast<const float4*>(g)[t];
  float4 bb = reinterpret_cast<const float4*>(b)[t];
  ushort4 rq = {f2bf(d0 * inv * gg.x + bb.x), f2bf(d1 * inv * gg.y + bb.y),
                f2bf(d2 * inv * gg.z + bb.z), f2bf(d3 * inv * gg.w + bb.w)};
  reinterpret_cast<ushort4*>(q + (size_t)bs * kD)[t] = rq;
}

// ---------------- fused MFMA GEMM, 3-deep pipelined ----------------
// C[M][N] = A[M][256] @ W[N][256]^T + bias (+modes) with optional fused row-LN.
// Tile 128m x 256n, 8 waves (2m x 4n), BK=32 (8 K-steps), 3 LDS buffers,
// counted vmcnt (6/3/0), raw s_barrier, T2 XOR-swizzle (slot ^= row&3) with
// pre-swizzled global source for global_load_lds.
// MODE: 0 plain, 1 relu, 2 +R, 3 +R then *mask
// LN:   0 none, 1 write LN(v) to C, 2 write v to C and LN(v) to C2
template <int MODE, int LN>
__global__ __launch_bounds__(512, 4) void gemm_fused(
    const unsigned short* __restrict__ A, const unsigned short* __restrict__ W,
    const float* __restrict__ bias, const unsigned short* __restrict__ R,
    const int* __restrict__ logseq, const float* __restrict__ lng,
    const float* __restrict__ lnb, unsigned short* __restrict__ C,
    unsigned short* __restrict__ C2, int N) {
  __shared__ __attribute__((aligned(16))) unsigned short As[3][128 * 32];
  __shared__ __attribute__((aligned(16))) unsigned short Ws[3][256 * 32];
  __shared__ float red1[128][4];
  __shared__ float red2[128][4];
  const int tid = threadIdx.x, lane = tid & 63, wid = tid >> 6;
  const int m0 = blockIdx.x * 128, n0 = blockIdx.y * 256;
  const int wm = wid >> 2, wn = wid & 3;
  const int lrow = lane & 15, kgrp = lane >> 4;
  // pre-swizzled staging sources: lane covers LDS row=tid>>2, slot t=tid&3;
  // content must be global slot t^(row&3)
  const int srow = tid >> 2;
  const int sslot = (tid & 3) ^ (srow & 3);
  const unsigned short* gA  = A + (size_t)(m0 + srow) * kD + sslot * 8;
  const unsigned short* gW0 = W + (size_t)(n0 + srow) * kD + sslot * 8;
  const unsigned short* gW1 = gW0 + (size_t)128 * kD;
  const int sa = (kgrp ^ (lrow & 3)) * 8;  // swizzled k-slot for fragment reads

#define STAGE(kk, bb)                                    \
  do {                                                   \
    gload16(gA + (kk) * 32, &As[bb][wid * 512]);         \
    gload16(gW0 + (kk) * 32, &Ws[bb][wid * 512]);        \
    gload16(gW1 + (kk) * 32, &Ws[bb][4096 + wid * 512]); \
  } while (0)

  f32x4 acc[4][4] = {};
  STAGE(0, 0);
  STAGE(1, 1);
  STAGE(2, 2);
#pragma unroll
  for (int k = 0; k < 8; ++k) {
    if (k <= 5) vm6(); else if (k == 6) vm3(); else vm0();
    bar();
    const int buf = k % 3;
    bf16x8 af[4], bfr[4];
#pragma unroll
    for (int x = 0; x < 4; ++x) {
      af[x]  = *reinterpret_cast<const bf16x8*>(&Ws[buf][(wn * 64 + x * 16 + lrow) * 32 + sa]);
      bfr[x] = *reinterpret_cast<const bf16x8*>(&As[buf][(wm * 64 + x * 16 + lrow) * 32 + sa]);
    }
    __builtin_amdgcn_s_setprio(1);
#pragma unroll
    for (int na = 0; na < 4; ++na)
#pragma unroll
      for (int mb = 0; mb < 4; ++mb)
        acc[na][mb] = __builtin_amdgcn_mfma_f32_16x16x32_bf16(
            af[na], bfr[mb], acc[na][mb], 0, 0, 0);
    __builtin_amdgcn_s_setprio(0);
    bar();
    if (k + 3 < 8) STAGE(k + 3, buf);
  }
#undef STAGE
  // ---- epilogue: v = acc + bias (+R) (relu) (*mask); LN partials ----
  float msk[4];
  if (MODE == 3) {
#pragma unroll
    for (int mb = 0; mb < 4; ++mb)
      msk[mb] = (logseq[m0 + wm * 64 + mb * 16 + lrow] != 0) ? 1.f : 0.f;
  }
  float s1[4] = {0.f, 0.f, 0.f, 0.f}, s2[4] = {0.f, 0.f, 0.f, 0.f};
#pragma unroll
  for (int na = 0; na < 4; ++na) {
    int gcol = n0 + wn * 64 + na * 16 + kgrp * 4;
    float4 b4 = *reinterpret_cast<const float4*>(bias + gcol);
    float bx[4] = {b4.x, b4.y, b4.z, b4.w};
#pragma unroll
    for (int mb = 0; mb < 4; ++mb) {
      int m = m0 + wm * 64 + mb * 16 + lrow;
      f32x4 v = acc[na][mb];
      ushort4 rv;
      if (MODE >= 2)
        rv = *reinterpret_cast<const ushort4*>(R + (size_t)m * N + gcol);
#pragma unroll
      for (int r = 0; r < 4; ++r) {
        float x = v[r] + bx[r];
        if (MODE == 1) x = fmaxf(x, 0.f);
        if (MODE >= 2) x += bf2f(reinterpret_cast<const unsigned short*>(&rv)[r]);
        if (MODE == 3) x *= msk[mb];
        v[r] = x;
        if (LN) { s1[mb] += x; s2[mb] += x * x; }
      }
      acc[na][mb] = v;
    }
  }
  float mean[4], inv[4];
  if (LN) {
#pragma unroll
    for (int mb = 0; mb < 4; ++mb) {
      s1[mb] += __shfl_xor(s1[mb], 16); s1[mb] += __shfl_xor(s1[mb], 32);
      s2[mb] += __shfl_xor(s2[mb], 16); s2[mb] += __shfl_xor(s2[mb], 32);
    }
    if (kgrp == 0) {
#pragma unroll
      for (int mb = 0; mb < 4; ++mb) {
        int rl = wm * 64 + mb * 16 + lrow;
        red1[rl][wn] = s1[mb];
        red2[rl][wn] = s2[mb];
      }
    }
    __syncthreads();
#pragma unroll
    for (int mb = 0; mb < 4; ++mb) {
      int rl = wm * 64 + mb * 16 + lrow;
      float4 p1 = *reinterpret_cast<const float4*>(red1[rl]);
      float4 p2 = *reinterpret_cast<const float4*>(red2[rl]);
      float t1 = p1.x + p1.y + p1.z + p1.w;
      float t2 = p2.x + p2.y + p2.z + p2.w;
      float mu = t1 * (1.f / 256.f);
      float var = t2 * (1.f / 256.f) - mu * mu;
      mean[mb] = mu;
      inv[mb] = rsqrtf(fmaxf(var, 0.f) + kEps);
    }
  }
#pragma unroll
  for (int na = 0; na < 4; ++na) {
    int gcol = n0 + wn * 64 + na * 16 + kgrp * 4;
    float gg[4], lb[4];
    if (LN) {
      float4 g4 = *reinterpret_cast<const float4*>(lng + gcol);
      float4 b4 = *reinterpret_cast<const float4*>(lnb + gcol);
      gg[0] = g4.x; gg[1] = g4.y; gg[2] = g4.z; gg[3] = g4.w;
      lb[0] = b4.x; lb[1] = b4.y; lb[2] = b4.z; lb[3] = b4.w;
    }
#pragma unroll
    for (int mb = 0; mb < 4; ++mb) {
      int m = m0 + wm * 64 + mb * 16 + lrow;
      f32x4 v = acc[na][mb];
      if (LN == 2 || LN == 0) {
        ushort4 o = {f2bf(v[0]), f2bf(v[1]), f2bf(v[2]), f2bf(v[3])};
        *reinterpret_cast<ushort4*>(C + (size_t)m * N + gcol) = o;
      }
      if (LN) {
        ushort4 o;
        unsigned short* os = reinterpret_cast<unsigned short*>(&o);
#pragma unroll
        for (int r = 0; r < 4; ++r)
          os[r] = f2bf((v[r] - mean[mb]) * inv[mb] * gg[r] + lb[r]);
        unsigned short* dst = (LN == 2) ? C2 : C;
        *reinterpret_cast<ushort4*>(dst + (size_t)m * 256 + gcol) = o;
      }
    }
  }
}

// ---------------- MFMA flash attention ----------------
// One block per (b,h). K[200][72] + V^T[64][216] staged in LDS.
// Swapped QK^T: S^T[key][q] = mfma(A=K, B=Q^T); PV: O^T[d][q] = mfma(A=Vt, B=P^T).
__global__ __launch_bounds__(256) void attn_mfma(
    const unsigned short* __restrict__ qbuf,
    const unsigned short* __restrict__ kv,
    unsigned short* __restrict__ obuf) {
  __shared__ __attribute__((aligned(16))) unsigned short Kl[200 * 72];
  __shared__ __attribute__((aligned(16))) unsigned short Vt[64 * 216];
  __shared__ __attribute__((aligned(16))) unsigned short Pt[4][16 * 40];
  int b = blockIdx.x >> 2, h = blockIdx.x & 3;
  int tid = threadIdx.x, lane = tid & 63, wid = tid >> 6;
  const unsigned short* kvb = kv + (size_t)b * kS * 512 + h * 64;
  for (int i = tid; i < 1600; i += 256) {
    int row = i >> 3, c = i & 7;
    *reinterpret_cast<uint4*>(&Kl[row * 72 + c * 8]) =
        *reinterpret_cast<const uint4*>(kvb + (size_t)row * 512 + c * 8);
  }
  for (int i = tid; i < 3200; i += 256) {
    int row = i >> 4, d0 = (i & 15) * 4;
    ushort4 v = *reinterpret_cast<const ushort4*>(kvb + 256 + (size_t)row * 512 + d0);
    Vt[(d0 + 0) * 216 + row] = v.x;
    Vt[(d0 + 1) * 216 + row] = v.y;
    Vt[(d0 + 2) * 216 + row] = v.z;
    Vt[(d0 + 3) * 216 + row] = v.w;
  }
  for (int i = tid; i < 1024; i += 256) {
    int d = i >> 4, c = i & 15;
    Vt[d * 216 + 200 + c] = 0;
  }
  __syncthreads();

  int qcol = lane & 15, kgrp = lane >> 4;
  const float scale2 = 0.18033688f;  // (1/8) * log2(e)
  int packed = (wid < 2) ? (wid == 0 ? 0xF45C : 0xF37B)
                         : (wid == 2 ? 0xF26A : 0x0189);
  for (int ti = 0; ti < 4; ++ti) {
    int t = (packed >> (ti * 4)) & 15;
    if (t == 15) break;
    int qb = t * 16;
    int qrow = qb + qcol;
    int qm = min(qrow, kS - 1);
    const unsigned short* qrp = qbuf + (size_t)(b * kS + qm) * kD + h * 64;
    bf16x8 qf0 = *reinterpret_cast<const bf16x8*>(qrp + kgrp * 8);
    bf16x8 qf1 = *reinterpret_cast<const bf16x8*>(qrp + 32 + kgrp * 8);
    f32x4 accO[4] = {};
    float m_run = -3.0e38f, l_run = 0.f;
    int nc = (qb + 47) >> 5;
    for (int c = 0; c < nc; ++c) {
      int kbase = c * 32;
      f32x4 s0 = {}, s1 = {};
      int kr0 = min(kbase + qcol, kS - 1);
      int kr1 = min(kbase + 16 + qcol, kS - 1);
      const unsigned short* K0 = &Kl[kr0 * 72 + kgrp * 8];
      const unsigned short* K1 = &Kl[kr1 * 72 + kgrp * 8];
      s0 = __builtin_amdgcn_mfma_f32_16x16x32_bf16(*reinterpret_cast<const bf16x8*>(K0), qf0, s0, 0, 0, 0);
      s0 = __builtin_amdgcn_mfma_f32_16x16x32_bf16(*reinterpret_cast<const bf16x8*>(K0 + 32), qf1, s0, 0, 0, 0);
      s1 = __builtin_amdgcn_mfma_f32_16x16x32_bf16(*reinterpret_cast<const bf16x8*>(K1), qf0, s1, 0, 0, 0);
      s1 = __builtin_amdgcn_mfma_f32_16x16x32_bf16(*reinterpret_cast<const bf16x8*>(K1 + 32), qf1, s1, 0, 0, 0);
      float sv[8];
      float cm = -3.0e38f;
#pragma unroll
      for (int r = 0; r < 4; ++r) {
        int key0 = kbase + kgrp * 4 + r;
        int key1 = key0 + 16;
        float x0 = (key0 <= qm) ? s0[r] * scale2 : -3.0e38f;
        float x1 = (key1 <= qm) ? s1[r] * scale2 : -3.0e38f;
        sv[r] = x0; sv[r + 4] = x1;
        cm = fmaxf(cm, fmaxf(x0, x1));
      }
      cm = fmaxf(cm, __shfl_xor(cm, 16));
      cm = fmaxf(cm, __shfl_xor(cm, 32));
      // T13 defer-max: skip rescale while chunk max stays within 2^8 of m_run
      if (!__all(cm - m_run <= 8.f)) {
        float m_new = fmaxf(m_run, cm);
        float sc = exp2f(m_run - m_new);
        l_run *= sc;
#pragma unroll
        for (int nf = 0; nf < 4; ++nf) accO[nf] *= sc;
        m_run = m_new;
      }
      float psum = 0.f;
      unsigned short pk[8];
#pragma unroll
      for (int r = 0; r < 8; ++r) {
        float p = exp2f(sv[r] - m_run);
        psum += p;
        pk[r] = f2bf(p);
      }
      l_run += psum;
      ushort4 w0 = {pk[0], pk[1], pk[2], pk[3]};
      ushort4 w1 = {pk[4], pk[5], pk[6], pk[7]};
      *reinterpret_cast<ushort4*>(&Pt[wid][qcol * 40 + kgrp * 4]) = w0;
      *reinterpret_cast<ushort4*>(&Pt[wid][qcol * 40 + 16 + kgrp * 4]) = w1;
      bf16x8 pf = *reinterpret_cast<const bf16x8*>(&Pt[wid][qcol * 40 + kgrp * 8]);
#pragma unroll
      for (int nf = 0; nf < 4; ++nf) {
        bf16x8 vf = *reinterpret_cast<const bf16x8*>(
            &Vt[(nf * 16 + qcol) * 216 + kbase + kgrp * 8]);
        accO[nf] = __builtin_amdgcn_mfma_f32_16x16x32_bf16(vf, pf, accO[nf], 0, 0, 0);
      }
    }
    float l_tot = l_run;
    l_tot += __shfl_xor(l_tot, 16);
    l_tot += __shfl_xor(l_tot, 32);
    float inv = 1.f / l_tot;
    if (qrow < kS) {
      unsigned short* op = obuf + (size_t)(b * kS + qrow) * kD + h * 64;
#pragma unroll
      for (int nf = 0; nf < 4; ++nf) {
        ushort4 o4 = {f2bf(accO[nf][0] * inv), f2bf(accO[nf][1] * inv),
                      f2bf(accO[nf][2] * inv), f2bf(accO[nf][3] * inv)};
        *reinterpret_cast<ushort4*>(op + nf * 16 + kgrp * 4) = o4;
      }
    }
  }
}

// ---------------- logits ----------------
__global__ __launch_bounds__(64) void logits_kernel(
    const unsigned short* __restrict__ feats, const float* __restrict__ item_emb,
    const int* __restrict__ pos_seqs, const int* __restrict__ neg_seqs,
    float* __restrict__ out) {
  int bs = blockIdx.x;
  int t = threadIdx.x;
  ushort4 f4 = reinterpret_cast<const ushort4*>(feats + (size_t)bs * kD)[t];
  float fx = bf2f(f4.x), fy = bf2f(f4.y), fz = bf2f(f4.z), fw = bf2f(f4.w);
  int pi = pos_seqs[bs], ni = neg_seqs[bs];
  float4 p = reinterpret_cast<const float4*>(item_emb + (size_t)pi * kD)[t];
  float4 n = reinterpret_cast<const float4*>(item_emb + (size_t)ni * kD)[t];
  float dp = fx * p.x + fy * p.y + fz * p.z + fw * p.w;
  float dn = fx * n.x + fy * n.y + fz * n.z + fw * n.w;
#pragma unroll
  for (int o = 32; o >= 1; o >>= 1) {
    dp += __shfl_xor(dp, o);
    dn += __shfl_xor(dn, o);
  }
  if (t == 0) {
    out[bs] = dp;
    out[(size_t)kB * kS + bs] = dn;
  }
}

}  // namespace

extern "C" void kernel_launch(void* const* d_in, const int* in_sizes, int n_in,
                              void* d_out, int out_size, void* d_ws,
                              size_t ws_size, hipStream_t stream) {
  const float* item_emb = (const float*)d_in[0];
  const float* pos_emb  = (const float*)d_in[1];
  const float* ln1_g = (const float*)d_in[2];
  const float* ln1_b = (const float*)d_in[3];
  const float* in_w  = (const float*)d_in[4];   // [2,768,256]
  const float* in_b  = (const float*)d_in[5];   // [2,768]
  const float* out_w = (const float*)d_in[6];   // [2,256,256]
  const float* out_b = (const float*)d_in[7];
  const float* ln2_g = (const float*)d_in[8];
  const float* ln2_b = (const float*)d_in[9];
  const float* c1_w  = (const float*)d_in[10];
  const float* c1_b  = (const float*)d_in[11];
  const float* c2_w  = (const float*)d_in[12];
  const float* c2_b  = (const float*)d_in[13];
  const float* last_g = (const float*)d_in[14];
  const float* last_b = (const float*)d_in[15];
  const int* log_seqs = (const int*)d_in[17];
  const int* pos_seqs = (const int*)d_in[18];
  const int* neg_seqs = (const int*)d_in[19];
  float* out = (float*)d_out;

  size_t unit = (size_t)kM * kD;
  unsigned short* U0 = (unsigned short*)d_ws;
  unsigned short* U[4] = {U0, U0 + unit, U0 + 2 * unit, U0 + 3 * unit};
  unsigned short* inw_bf  = U0 + 4 * unit;
  unsigned short* outw_bf = inw_bf + 2 * 768 * 256;
  unsigned short* c1w_bf  = outw_bf + 2 * 256 * 256;
  unsigned short* c2w_bf  = c1w_bf + 2 * 256 * 256;

  cvt_kernel<<<2 * 768 * 256 / 1024, 256, 0, stream>>>(in_w, inw_bf, 2 * 768 * 256);
  cvt_kernel<<<2 * 256 * 256 / 1024, 256, 0, stream>>>(out_w, outw_bf, 2 * 256 * 256);
  cvt_kernel<<<2 * 256 * 256 / 1024, 256, 0, stream>>>(c1_w, c1w_bf, 2 * 256 * 256);
  cvt_kernel<<<2 * 256 * 256 / 1024, 256, 0, stream>>>(c2_w, c2w_bf, 2 * 256 * 256);

  // U0 = seqs0, U1 = Q0 (LN1 fused)
  embed_ln_kernel<<<kM, 64, 0, stream>>>(item_emb, pos_emb, log_seqs,
                                         ln1_g, ln1_b, U[0], U[1]);

  dim3 g1(kM / 128, 1), g2(kM / 128, 2);
  // ---- layer 0 ----
  const unsigned short* iw0 = inw_bf;
  gemm_fused<0, 0><<<g2, 512, 0, stream>>>(U[0], iw0 + 256 * kD, in_b + 256,
      nullptr, nullptr, nullptr, nullptr, U[2], nullptr, 512);           // kv -> U2|U3
  gemm_fused<0, 0><<<g1, 512, 0, stream>>>(U[1], iw0, in_b,
      nullptr, nullptr, nullptr, nullptr, U[0], nullptr, 256);           // q -> U0
  attn_mfma<<<kB * kH, 256, 0, stream>>>(U[0], U[2], U[0]);              // o -> U0
  gemm_fused<2, 1><<<g1, 512, 0, stream>>>(U[0], outw_bf, out_b,
      U[1], nullptr, ln2_g, ln2_b, U[1], nullptr, 256);                  // ln2 -> U1
  gemm_fused<1, 0><<<g1, 512, 0, stream>>>(U[1], c1w_bf, c1_b,
      nullptr, nullptr, nullptr, nullptr, U[0], nullptr, 256);           // h1 -> U0
  gemm_fused<3, 2><<<g1, 512, 0, stream>>>(U[0], c2w_bf, c2_b,
      U[1], log_seqs, ln1_g + 256, ln1_b + 256, U[2], U[3], 256);        // seqs1->U2, Q1->U3
  // ---- layer 1 ----
  const unsigned short* iw1 = inw_bf + (size_t)768 * 256;
  gemm_fused<0, 0><<<g2, 512, 0, stream>>>(U[2], iw1 + 256 * kD, in_b + 768 + 256,
      nullptr, nullptr, nullptr, nullptr, U[0], nullptr, 512);           // kv -> U0|U1
  gemm_fused<0, 0><<<g1, 512, 0, stream>>>(U[3], iw1, in_b + 768,
      nullptr, nullptr, nullptr, nullptr, U[2], nullptr, 256);           // q -> U2
  attn_mfma<<<kB * kH, 256, 0, stream>>>(U[2], U[0], U[2]);              // o -> U2
  gemm_fused<2, 1><<<g1, 512, 0, stream>>>(U[2], outw_bf + 256 * 256, out_b + 256,
      U[3], nullptr, ln2_g + 256, ln2_b + 256, U[3], nullptr, 256);      // ln2 -> U3
  gemm_fused<1, 0><<<g1, 512, 0, stream>>>(U[3], c1w_bf + 256 * 256, c1_b + 256,
      nullptr, nullptr, nullptr, nullptr, U[2], nullptr, 256);           // h1 -> U2
  gemm_fused<3, 1><<<g1, 512, 0, stream>>>(U[2], c2w_bf + 256 * 256, c2_b + 256,
      U[3], log_seqs, last_g, last_b, U[0], nullptr, 256);               // feats -> U0

  logits_kernel<<<kM, 64, 0, stream>>>(U[0], item_emb, pos_seqs, neg_seqs, out);
}

// Round 6
// 784.813 us; speedup vs baseline: 7.5678x; 1.0047x over previous
//
#include <hip/hip_runtime.h>
#include <math.h>

namespace {

constexpr int kB = 512, kS = 200, kD = 256, kH = 4, kDH = 64;
constexpr int kM = kB * kS;           // 102400 rows
constexpr float kEps = 1e-8f;

typedef short bf16x8 __attribute__((ext_vector_type(8)));   // 8 bf16 = 4 VGPR
typedef float f32x4 __attribute__((ext_vector_type(4)));

__device__ __forceinline__ float bf2f(unsigned short s) {
  return __uint_as_float(((unsigned)s) << 16);
}
__device__ __forceinline__ unsigned short f2bf(float f) {
  unsigned u = __float_as_uint(f);
  return (unsigned short)((u + 0x7fffu + ((u >> 16) & 1u)) >> 16);
}
// two f32 -> packed 2xbf16 (RNE), single instruction
__device__ __forceinline__ unsigned cvtpk(float lo, float hi) {
  unsigned r;
  asm("v_cvt_pk_bf16_f32 %0, %1, %2" : "=v"(r) : "v"(lo), "v"(hi));
  return r;
}
__device__ __forceinline__ void gload16(const void* g, void* l) {
  __builtin_amdgcn_global_load_lds(
      (const __attribute__((address_space(1))) void*)g,
      (__attribute__((address_space(3))) void*)l, 16, 0, 0);
}
__device__ __forceinline__ void vm6() { asm volatile("s_waitcnt vmcnt(6)" ::: "memory"); }
__device__ __forceinline__ void vm3() { asm volatile("s_waitcnt vmcnt(3)" ::: "memory"); }
__device__ __forceinline__ void vm0() { asm volatile("s_waitcnt vmcnt(0)" ::: "memory"); }
__device__ __forceinline__ void bar() { asm volatile("s_barrier" ::: "memory"); }

// ---------------- weights f32 -> bf16 (4 tensors, one dispatch) ----------------
__global__ __launch_bounds__(256) void cvt4_kernel(
    const float* __restrict__ w0, const float* __restrict__ w1,
    const float* __restrict__ w2, const float* __restrict__ w3,
    unsigned short* __restrict__ o0, unsigned short* __restrict__ o1,
    unsigned short* __restrict__ o2, unsigned short* __restrict__ o3) {
  int blk = blockIdx.x;
  const float* src;
  unsigned short* dst;
  int base;
  if (blk < 384)      { src = w0; dst = o0; base = blk; }
  else if (blk < 512) { src = w1; dst = o1; base = blk - 384; }
  else if (blk < 640) { src = w2; dst = o2; base = blk - 512; }
  else                { src = w3; dst = o3; base = blk - 640; }
  int i4 = (base * 256 + threadIdx.x) * 4;
  float4 v = *reinterpret_cast<const float4*>(src + i4);
  uint2 o = {cvtpk(v.x, v.y), cvtpk(v.z, v.w)};
  *reinterpret_cast<uint2*>(dst + i4) = o;
}

// ---------------- embed + fused LN1(layer0) ----------------
__global__ __launch_bounds__(64) void embed_ln_kernel(
    const float* __restrict__ item_emb, const float* __restrict__ pos_emb,
    const int* __restrict__ log_seqs, const float* __restrict__ g,
    const float* __restrict__ b, unsigned short* __restrict__ seqs,
    unsigned short* __restrict__ q) {
  int bs = blockIdx.x;
  int s = bs % kS;
  int idx = log_seqs[bs];
  float msk = (idx != 0) ? 1.f : 0.f;
  int t = threadIdx.x;
  float4 a = reinterpret_cast<const float4*>(item_emb + (size_t)idx * kD)[t];
  float4 p = reinterpret_cast<const float4*>(pos_emb + (size_t)s * kD)[t];
  float v[4];
  v[0] = (a.x * 16.f + p.x) * msk;
  v[1] = (a.y * 16.f + p.y) * msk;
  v[2] = (a.z * 16.f + p.z) * msk;
  v[3] = (a.w * 16.f + p.w) * msk;
  uint2 r = {cvtpk(v[0], v[1]), cvtpk(v[2], v[3])};
  reinterpret_cast<uint2*>(seqs + (size_t)bs * kD)[t] = r;
  float sm = v[0] + v[1] + v[2] + v[3];
#pragma unroll
  for (int o = 32; o >= 1; o >>= 1) sm += __shfl_xor(sm, o);
  float mean = sm * (1.f / kD);
  float d0 = v[0] - mean, d1 = v[1] - mean, d2 = v[2] - mean, d3 = v[3] - mean;
  float vs = d0 * d0 + d1 * d1 + d2 * d2 + d3 * d3;
#pragma unroll
  for (int o = 32; o >= 1; o >>= 1) vs += __shfl_xor(vs, o);
  float inv = rsqrtf(vs * (1.f / kD) + kEps);
  float4 gg = reinterpret_cast<const float4*>(g)[t];
  float4 bb = reinterpret_cast<const float4*>(b)[t];
  uint2 rq = {cvtpk(d0 * inv * gg.x + bb.x, d1 * inv * gg.y + bb.y),
              cvtpk(d2 * inv * gg.z + bb.z, d3 * inv * gg.w + bb.w)};
  reinterpret_cast<uint2*>(q + (size_t)bs * kD)[t] = rq;
}

// ---------------- fused MFMA GEMM, 3-deep pipelined ----------------
// C[M][N] = A[M][256] @ W[N][256]^T + bias (+modes) with optional fused row-LN.
// Tile 128m x 256n, 8 waves (2m x 4n), BK=32 (8 K-steps), 3 LDS buffers,
// counted vmcnt (6/3/0), raw s_barrier, T2 XOR-swizzle with pre-swizzled
// global source for global_load_lds.
// MODE: 0 plain, 1 relu, 2 +R, 3 +R then *mask
// LN:   0 none, 1 write LN(v) to C, 2 write v to C and LN(v) to C2
template <int MODE, int LN>
__global__ __launch_bounds__(512, 4) void gemm_fused(
    const unsigned short* __restrict__ A, const unsigned short* __restrict__ W,
    const float* __restrict__ bias, const unsigned short* __restrict__ R,
    const int* __restrict__ logseq, const float* __restrict__ lng,
    const float* __restrict__ lnb, unsigned short* __restrict__ C,
    unsigned short* __restrict__ C2, int N) {
  __shared__ __attribute__((aligned(16))) unsigned short As[3][128 * 32];
  __shared__ __attribute__((aligned(16))) unsigned short Ws[3][256 * 32];
  __shared__ float red1[128][4];
  __shared__ float red2[128][4];
  const int tid = threadIdx.x, lane = tid & 63, wid = tid >> 6;
  const int m0 = blockIdx.x * 128, n0 = blockIdx.y * 256;
  const int wm = wid >> 2, wn = wid & 3;
  const int lrow = lane & 15, kgrp = lane >> 4;
  const int srow = tid >> 2;
  const int sslot = (tid & 3) ^ (srow & 3);
  const unsigned short* gA  = A + (size_t)(m0 + srow) * kD + sslot * 8;
  const unsigned short* gW0 = W + (size_t)(n0 + srow) * kD + sslot * 8;
  const unsigned short* gW1 = gW0 + (size_t)128 * kD;
  const int sa = (kgrp ^ (lrow & 3)) * 8;  // swizzled k-slot for fragment reads

#define STAGE(kk, bb)                                    \
  do {                                                   \
    gload16(gA + (kk) * 32, &As[bb][wid * 512]);         \
    gload16(gW0 + (kk) * 32, &Ws[bb][wid * 512]);        \
    gload16(gW1 + (kk) * 32, &Ws[bb][4096 + wid * 512]); \
  } while (0)

  f32x4 acc[4][4] = {};
  STAGE(0, 0);
  STAGE(1, 1);
  STAGE(2, 2);
#pragma unroll
  for (int k = 0; k < 8; ++k) {
    if (k <= 5) vm6(); else if (k == 6) vm3(); else vm0();
    bar();
    const int buf = k % 3;
    bf16x8 af[4], bfr[4];
#pragma unroll
    for (int x = 0; x < 4; ++x) {
      af[x]  = *reinterpret_cast<const bf16x8*>(&Ws[buf][(wn * 64 + x * 16 + lrow) * 32 + sa]);
      bfr[x] = *reinterpret_cast<const bf16x8*>(&As[buf][(wm * 64 + x * 16 + lrow) * 32 + sa]);
    }
    __builtin_amdgcn_s_setprio(1);
#pragma unroll
    for (int na = 0; na < 4; ++na)
#pragma unroll
      for (int mb = 0; mb < 4; ++mb)
        acc[na][mb] = __builtin_amdgcn_mfma_f32_16x16x32_bf16(
            af[na], bfr[mb], acc[na][mb], 0, 0, 0);
    __builtin_amdgcn_s_setprio(0);
    bar();
    if (k + 3 < 8) STAGE(k + 3, buf);
  }
#undef STAGE
  // ---- epilogue ----
  float msk[4];
  if (MODE == 3) {
#pragma unroll
    for (int mb = 0; mb < 4; ++mb)
      msk[mb] = (logseq[m0 + wm * 64 + mb * 16 + lrow] != 0) ? 1.f : 0.f;
  }
  float s1[4] = {0.f, 0.f, 0.f, 0.f}, s2[4] = {0.f, 0.f, 0.f, 0.f};
#pragma unroll
  for (int na = 0; na < 4; ++na) {
    int gcol = n0 + wn * 64 + na * 16 + kgrp * 4;
    float4 b4 = *reinterpret_cast<const float4*>(bias + gcol);
    float bx[4] = {b4.x, b4.y, b4.z, b4.w};
#pragma unroll
    for (int mb = 0; mb < 4; ++mb) {
      int m = m0 + wm * 64 + mb * 16 + lrow;
      f32x4 v = acc[na][mb];
      ushort4 rv;
      if (MODE >= 2)
        rv = *reinterpret_cast<const ushort4*>(R + (size_t)m * N + gcol);
#pragma unroll
      for (int r = 0; r < 4; ++r) {
        float x = v[r] + bx[r];
        if (MODE == 1) x = fmaxf(x, 0.f);
        if (MODE >= 2) x += bf2f(reinterpret_cast<const unsigned short*>(&rv)[r]);
        if (MODE == 3) x *= msk[mb];
        v[r] = x;
        if (LN) { s1[mb] += x; s2[mb] += x * x; }
      }
      acc[na][mb] = v;
    }
  }
  float mean[4], inv[4];
  if (LN) {
#pragma unroll
    for (int mb = 0; mb < 4; ++mb) {
      s1[mb] += __shfl_xor(s1[mb], 16); s1[mb] += __shfl_xor(s1[mb], 32);
      s2[mb] += __shfl_xor(s2[mb], 16); s2[mb] += __shfl_xor(s2[mb], 32);
    }
    if (kgrp == 0) {
#pragma unroll
      for (int mb = 0; mb < 4; ++mb) {
        int rl = wm * 64 + mb * 16 + lrow;
        red1[rl][wn] = s1[mb];
        red2[rl][wn] = s2[mb];
      }
    }
    __syncthreads();
#pragma unroll
    for (int mb = 0; mb < 4; ++mb) {
      int rl = wm * 64 + mb * 16 + lrow;
      float4 p1 = *reinterpret_cast<const float4*>(red1[rl]);
      float4 p2 = *reinterpret_cast<const float4*>(red2[rl]);
      float t1 = p1.x + p1.y + p1.z + p1.w;
      float t2 = p2.x + p2.y + p2.z + p2.w;
      float mu = t1 * (1.f / 256.f);
      float var = t2 * (1.f / 256.f) - mu * mu;
      mean[mb] = mu;
      inv[mb] = rsqrtf(fmaxf(var, 0.f) + kEps);
    }
  }
#pragma unroll
  for (int na = 0; na < 4; ++na) {
    int gcol = n0 + wn * 64 + na * 16 + kgrp * 4;
    float gg[4], lb[4];
    if (LN) {
      float4 g4 = *reinterpret_cast<const float4*>(lng + gcol);
      float4 b4 = *reinterpret_cast<const float4*>(lnb + gcol);
      gg[0] = g4.x; gg[1] = g4.y; gg[2] = g4.z; gg[3] = g4.w;
      lb[0] = b4.x; lb[1] = b4.y; lb[2] = b4.z; lb[3] = b4.w;
    }
#pragma unroll
    for (int mb = 0; mb < 4; ++mb) {
      int m = m0 + wm * 64 + mb * 16 + lrow;
      f32x4 v = acc[na][mb];
      if (LN == 2 || LN == 0) {
        uint2 o = {cvtpk(v[0], v[1]), cvtpk(v[2], v[3])};
        *reinterpret_cast<uint2*>(C + (size_t)m * N + gcol) = o;
      }
      if (LN) {
        float y0 = (v[0] - mean[mb]) * inv[mb] * gg[0] + lb[0];
        float y1 = (v[1] - mean[mb]) * inv[mb] * gg[1] + lb[1];
        float y2 = (v[2] - mean[mb]) * inv[mb] * gg[2] + lb[2];
        float y3 = (v[3] - mean[mb]) * inv[mb] * gg[3] + lb[3];
        uint2 o = {cvtpk(y0, y1), cvtpk(y2, y3)};
        unsigned short* dst = (LN == 2) ? C2 : C;
        *reinterpret_cast<uint2*>(dst + (size_t)m * 256 + gcol) = o;
      }
    }
  }
}

// ---------------- MFMA flash attention ----------------
// One block per (b,h). K[200][72] + V^T[64][234] staged in LDS.
// Vt stride 234 (117 words, odd) -> transpose stores ~4-way instead of 16-way.
__global__ __launch_bounds__(256) void attn_mfma(
    const unsigned short* __restrict__ qbuf,
    const unsigned short* __restrict__ kv,
    unsigned short* __restrict__ obuf) {
  constexpr int kVS = 234;
  __shared__ __attribute__((aligned(16))) unsigned short Kl[200 * 72];
  __shared__ __attribute__((aligned(16))) unsigned short Vt[64 * kVS];
  __shared__ __attribute__((aligned(16))) unsigned short Pt[4][16 * 40];
  int b = blockIdx.x >> 2, h = blockIdx.x & 3;
  int tid = threadIdx.x, lane = tid & 63, wid = tid >> 6;
  const unsigned short* kvb = kv + (size_t)b * kS * 512 + h * 64;
  for (int i = tid; i < 1600; i += 256) {
    int row = i >> 3, c = i & 7;
    *reinterpret_cast<uint4*>(&Kl[row * 72 + c * 8]) =
        *reinterpret_cast<const uint4*>(kvb + (size_t)row * 512 + c * 8);
  }
  for (int i = tid; i < 3200; i += 256) {
    int row = i >> 4, d0 = (i & 15) * 4;
    ushort4 v = *reinterpret_cast<const ushort4*>(kvb + 256 + (size_t)row * 512 + d0);
    Vt[(d0 + 0) * kVS + row] = v.x;
    Vt[(d0 + 1) * kVS + row] = v.y;
    Vt[(d0 + 2) * kVS + row] = v.z;
    Vt[(d0 + 3) * kVS + row] = v.w;
  }
  for (int i = tid; i < 2048; i += 256) {
    int d = i >> 5, c = i & 31;
    Vt[d * kVS + 200 + c] = 0;
  }
  __syncthreads();

  int qcol = lane & 15, kgrp = lane >> 4;
  const float scale2 = 0.18033688f;  // (1/8) * log2(e)
  int packed = (wid < 2) ? (wid == 0 ? 0xF45C : 0xF37B)
                         : (wid == 2 ? 0xF26A : 0x0189);
  for (int ti = 0; ti < 4; ++ti) {
    int t = (packed >> (ti * 4)) & 15;
    if (t == 15) break;
    int qb = t * 16;
    int qrow = qb + qcol;
    int qm = min(qrow, kS - 1);
    const unsigned short* qrp = qbuf + (size_t)(b * kS + qm) * kD + h * 64;
    bf16x8 qf0 = *reinterpret_cast<const bf16x8*>(qrp + kgrp * 8);
    bf16x8 qf1 = *reinterpret_cast<const bf16x8*>(qrp + 32 + kgrp * 8);
    f32x4 accO[4] = {};
    float m_run = -3.0e38f, l_run = 0.f;
    int nc = (qb + 47) >> 5;
    for (int c = 0; c < nc; ++c) {
      int kbase = c * 32;
      f32x4 s0 = {}, s1 = {};
      int kr0 = min(kbase + qcol, kS - 1);
      int kr1 = min(kbase + 16 + qcol, kS - 1);
      const unsigned short* K0 = &Kl[kr0 * 72 + kgrp * 8];
      const unsigned short* K1 = &Kl[kr1 * 72 + kgrp * 8];
      s0 = __builtin_amdgcn_mfma_f32_16x16x32_bf16(*reinterpret_cast<const bf16x8*>(K0), qf0, s0, 0, 0, 0);
      s0 = __builtin_amdgcn_mfma_f32_16x16x32_bf16(*reinterpret_cast<const bf16x8*>(K0 + 32), qf1, s0, 0, 0, 0);
      s1 = __builtin_amdgcn_mfma_f32_16x16x32_bf16(*reinterpret_cast<const bf16x8*>(K1), qf0, s1, 0, 0, 0);
      s1 = __builtin_amdgcn_mfma_f32_16x16x32_bf16(*reinterpret_cast<const bf16x8*>(K1 + 32), qf1, s1, 0, 0, 0);
      float sv[8];
      float cm = -3.0e38f;
#pragma unroll
      for (int r = 0; r < 4; ++r) {
        int key0 = kbase + kgrp * 4 + r;
        int key1 = key0 + 16;
        float x0 = (key0 <= qm) ? s0[r] * scale2 : -3.0e38f;
        float x1 = (key1 <= qm) ? s1[r] * scale2 : -3.0e38f;
        sv[r] = x0; sv[r + 4] = x1;
        cm = fmaxf(cm, fmaxf(x0, x1));
      }
      cm = fmaxf(cm, __shfl_xor(cm, 16));
      cm = fmaxf(cm, __shfl_xor(cm, 32));
      // T13 defer-max
      if (!__all(cm - m_run <= 8.f)) {
        float m_new = fmaxf(m_run, cm);
        float sc = exp2f(m_run - m_new);
        l_run *= sc;
#pragma unroll
        for (int nf = 0; nf < 4; ++nf) accO[nf] *= sc;
        m_run = m_new;
      }
      float p[8];
      float psum = 0.f;
#pragma unroll
      for (int r = 0; r < 8; ++r) {
        p[r] = exp2f(sv[r] - m_run);
        psum += p[r];
      }
      l_run += psum;
      uint2 w0 = {cvtpk(p[0], p[1]), cvtpk(p[2], p[3])};
      uint2 w1 = {cvtpk(p[4], p[5]), cvtpk(p[6], p[7])};
      *reinterpret_cast<uint2*>(&Pt[wid][qcol * 40 + kgrp * 4]) = w0;
      *reinterpret_cast<uint2*>(&Pt[wid][qcol * 40 + 16 + kgrp * 4]) = w1;
      bf16x8 pf = *reinterpret_cast<const bf16x8*>(&Pt[wid][qcol * 40 + kgrp * 8]);
#pragma unroll
      for (int nf = 0; nf < 4; ++nf) {
        bf16x8 vf = *reinterpret_cast<const bf16x8*>(
            &Vt[(nf * 16 + qcol) * kVS + kbase + kgrp * 8]);
        accO[nf] = __builtin_amdgcn_mfma_f32_16x16x32_bf16(vf, pf, accO[nf], 0, 0, 0);
      }
    }
    float l_tot = l_run;
    l_tot += __shfl_xor(l_tot, 16);
    l_tot += __shfl_xor(l_tot, 32);
    float inv = 1.f / l_tot;
    if (qrow < kS) {
      unsigned short* op = obuf + (size_t)(b * kS + qrow) * kD + h * 64;
#pragma unroll
      for (int nf = 0; nf < 4; ++nf) {
        uint2 o4 = {cvtpk(accO[nf][0] * inv, accO[nf][1] * inv),
                    cvtpk(accO[nf][2] * inv, accO[nf][3] * inv)};
        *reinterpret_cast<uint2*>(op + nf * 16 + kgrp * 4) = o4;
      }
    }
  }
}

// ---------------- logits ----------------
__global__ __launch_bounds__(64) void logits_kernel(
    const unsigned short* __restrict__ feats, const float* __restrict__ item_emb,
    const int* __restrict__ pos_seqs, const int* __restrict__ neg_seqs,
    float* __restrict__ out) {
  int bs = blockIdx.x;
  int t = threadIdx.x;
  ushort4 f4 = reinterpret_cast<const ushort4*>(feats + (size_t)bs * kD)[t];
  float fx = bf2f(f4.x), fy = bf2f(f4.y), fz = bf2f(f4.z), fw = bf2f(f4.w);
  int pi = pos_seqs[bs], ni = neg_seqs[bs];
  float4 p = reinterpret_cast<const float4*>(item_emb + (size_t)pi * kD)[t];
  float4 n = reinterpret_cast<const float4*>(item_emb + (size_t)ni * kD)[t];
  float dp = fx * p.x + fy * p.y + fz * p.z + fw * p.w;
  float dn = fx * n.x + fy * n.y + fz * n.z + fw * n.w;
#pragma unroll
  for (int o = 32; o >= 1; o >>= 1) {
    dp += __shfl_xor(dp, o);
    dn += __shfl_xor(dn, o);
  }
  if (t == 0) {
    out[bs] = dp;
    out[(size_t)kB * kS + bs] = dn;
  }
}

}  // namespace

extern "C" void kernel_launch(void* const* d_in, const int* in_sizes, int n_in,
                              void* d_out, int out_size, void* d_ws,
                              size_t ws_size, hipStream_t stream) {
  const float* item_emb = (const float*)d_in[0];
  const float* pos_emb  = (const float*)d_in[1];
  const float* ln1_g = (const float*)d_in[2];
  const float* ln1_b = (const float*)d_in[3];
  const float* in_w  = (const float*)d_in[4];   // [2,768,256]
  const float* in_b  = (const float*)d_in[5];   // [2,768]
  const float* out_w = (const float*)d_in[6];   // [2,256,256]
  const float* out_b = (const float*)d_in[7];
  const float* ln2_g = (const float*)d_in[8];
  const float* ln2_b = (const float*)d_in[9];
  const float* c1_w  = (const float*)d_in[10];
  const float* c1_b  = (const float*)d_in[11];
  const float* c2_w  = (const float*)d_in[12];
  const float* c2_b  = (const float*)d_in[13];
  const float* last_g = (const float*)d_in[14];
  const float* last_b = (const float*)d_in[15];
  const int* log_seqs = (const int*)d_in[17];
  const int* pos_seqs = (const int*)d_in[18];
  const int* neg_seqs = (const int*)d_in[19];
  float* out = (float*)d_out;

  size_t unit = (size_t)kM * kD;
  unsigned short* U0 = (unsigned short*)d_ws;
  unsigned short* U[4] = {U0, U0 + unit, U0 + 2 * unit, U0 + 3 * unit};
  unsigned short* inw_bf  = U0 + 4 * unit;
  unsigned short* outw_bf = inw_bf + 2 * 768 * 256;
  unsigned short* c1w_bf  = outw_bf + 2 * 256 * 256;
  unsigned short* c2w_bf  = c1w_bf + 2 * 256 * 256;

  cvt4_kernel<<<768, 256, 0, stream>>>(in_w, out_w, c1_w, c2_w,
                                       inw_bf, outw_bf, c1w_bf, c2w_bf);

  // U0 = seqs0, U1 = Q0 (LN1 fused)
  embed_ln_kernel<<<kM, 64, 0, stream>>>(item_emb, pos_emb, log_seqs,
                                         ln1_g, ln1_b, U[0], U[1]);

  dim3 g1(kM / 128, 1), g2(kM / 128, 2);
  // ---- layer 0 ----
  const unsigned short* iw0 = inw_bf;
  gemm_fused<0, 0><<<g2, 512, 0, stream>>>(U[0], iw0 + 256 * kD, in_b + 256,
      nullptr, nullptr, nullptr, nullptr, U[2], nullptr, 512);           // kv -> U2|U3
  gemm_fused<0, 0><<<g1, 512, 0, stream>>>(U[1], iw0, in_b,
      nullptr, nullptr, nullptr, nullptr, U[0], nullptr, 256);           // q -> U0
  attn_mfma<<<kB * kH, 256, 0, stream>>>(U[0], U[2], U[0]);              // o -> U0
  gemm_fused<2, 1><<<g1, 512, 0, stream>>>(U[0], outw_bf, out_b,
      U[1], nullptr, ln2_g, ln2_b, U[1], nullptr, 256);                  // ln2 -> U1
  gemm_fused<1, 0><<<g1, 512, 0, stream>>>(U[1], c1w_bf, c1_b,
      nullptr, nullptr, nullptr, nullptr, U[0], nullptr, 256);           // h1 -> U0
  gemm_fused<3, 2><<<g1, 512, 0, stream>>>(U[0], c2w_bf, c2_b,
      U[1], log_seqs, ln1_g + 256, ln1_b + 256, U[2], U[3], 256);        // seqs1->U2, Q1->U3
  // ---- layer 1 ----
  const unsigned short* iw1 = inw_bf + (size_t)768 * 256;
  gemm_fused<0, 0><<<g2, 512, 0, stream>>>(U[2], iw1 + 256 * kD, in_b + 768 + 256,
      nullptr, nullptr, nullptr, nullptr, U[0], nullptr, 512);           // kv -> U0|U1
  gemm_fused<0, 0><<<g1, 512, 0, stream>>>(U[3], iw1, in_b + 768,
      nullptr, nullptr, nullptr, nullptr, U[2], nullptr, 256);           // q -> U2
  attn_mfma<<<kB * kH, 256, 0, stream>>>(U[2], U[0], U[2]);              // o -> U2
  gemm_fused<2, 1><<<g1, 512, 0, stream>>>(U[2], outw_bf + 256 * 256, out_b + 256,
      U[3], nullptr, ln2_g + 256, ln2_b + 256, U[3], nullptr, 256);      // ln2 -> U3
  gemm_fused<1, 0><<<g1, 512, 0, stream>>>(U[3], c1w_bf + 256 * 256, c1_b + 256,
      nullptr, nullptr, nullptr, nullptr, U[2], nullptr, 256);           // h1 -> U2
  gemm_fused<3, 1><<<g1, 512, 0, stream>>>(U[2], c2w_bf + 256 * 256, c2_b + 256,
      U[3], log_seqs, last_g, last_b, U[0], nullptr, 256);               // feats -> U0

  logits_kernel<<<kM, 64, 0, stream>>>(U[0], item_emb, pos_seqs, neg_seqs, out);
}